// Round 6
// baseline (818.616 us; speedup 1.0000x reference)
//
#include <hip/hip_runtime.h>
#include <cmath>

#define CH 128          // scan chunk length
#define NC 32           // 4096 / CH

typedef __bf16 bf16_t;
typedef __attribute__((ext_vector_type(8))) __bf16 bf16x8;
typedef __attribute__((ext_vector_type(4))) __bf16 bf16x4;
typedef __attribute__((ext_vector_type(4))) float f32x4;

// CK idiom: generic->AS1/AS3 via uintptr for global_load_lds (width 16).
#define GLOAD_LDS16(gp, lp)                                                     \
    __builtin_amdgcn_global_load_lds(                                           \
        (const __attribute__((address_space(1))) unsigned int*)(uintptr_t)(gp), \
        (__attribute__((address_space(3))) unsigned int*)(uintptr_t)(lp),       \
        16, 0, 0)

// ---------------------------------------------------------------------------
// fp32 -> (hi, lo) bf16 split.  4 floats per thread.
// ---------------------------------------------------------------------------
__global__ __launch_bounds__(256) void split_hl(
    const float* __restrict__ in, bf16_t* __restrict__ hi,
    bf16_t* __restrict__ lo, int n4)
{
    const int i = blockIdx.x * 256 + threadIdx.x;
    if (i >= n4) return;
    const float4 v = ((const float4*)in)[i];
    const bf16_t h0 = (bf16_t)v.x, h1 = (bf16_t)v.y,
                 h2 = (bf16_t)v.z, h3 = (bf16_t)v.w;
    bf16x4 hv = {h0, h1, h2, h3};
    bf16x4 lv = {(bf16_t)(v.x - (float)h0), (bf16_t)(v.y - (float)h1),
                 (bf16_t)(v.z - (float)h2), (bf16_t)(v.w - (float)h3)};
    ((bf16x4*)hi)[i] = hv;
    ((bf16x4*)lo)[i] = lv;
}

// ---------------------------------------------------------------------------
// float4 add:  o = a + b   (split-K reduce)
// ---------------------------------------------------------------------------
__global__ __launch_bounds__(256) void add2(
    const float* __restrict__ a, const float* __restrict__ b,
    float* __restrict__ o, int n4)
{
    const int i = blockIdx.x * 256 + threadIdx.x;
    if (i >= n4) return;
    const float4 va = ((const float4*)a)[i];
    const float4 vb = ((const float4*)b)[i];
    ((float4*)o)[i] = make_float4(va.x + vb.x, va.y + vb.y,
                                  va.z + vb.z, va.w + vb.w);
}

// ---------------------------------------------------------------------------
// Split-precision MFMA NT-GEMM, all-bf16 staging:
//   C = Ah.Bh^T + Al.Bh^T + Ah.Bl^T      (A fp32 ~= Ah + Al)
// A pre-split [M][Ktot] bf16 pair; B pre-split [N][Ktot] bf16 pair.
// 128x128 tile, BK=32, 4 waves, 4x4 frags mfma_f32_16x16x32_bf16,
// 48 MFMA / k-step, 8x global_load_lds width-16 staging, 32 KB LDS.
// blockIdx.z selects a K-split: k in [z*Ksplit, (z+1)*Ksplit).
// EPI 0: (C + z*partStride)[m*ldc+n] = v     (split-K partial store)
// EPI 1: n<2048 -> C (x half), else -> C2 (z half)   [single split assumed]
// ---------------------------------------------------------------------------
template<int EPI>
__global__ __launch_bounds__(256) void gemm_mfma3p(
    const bf16_t* __restrict__ Ah, const bf16_t* __restrict__ Al,
    const bf16_t* __restrict__ Bh, const bf16_t* __restrict__ Bl,
    float* __restrict__ C, float* __restrict__ C2,
    int N, int Ktot, int Ksplit, int ldc, size_t partStride)
{
    __shared__ __align__(16) bf16_t Ash[128 * 32];
    __shared__ __align__(16) bf16_t Asl[128 * 32];
    __shared__ __align__(16) bf16_t Bsh[128 * 32];
    __shared__ __align__(16) bf16_t Bsl[128 * 32];

    const int tid  = threadIdx.x;
    const int lane = tid & 63;
    const int w    = tid >> 6;
    const int wr   = (w >> 1) * 64;
    const int wc   = (w & 1) * 64;
    const int bm   = blockIdx.x * 128;
    const int bn   = blockIdx.y * 128;
    const int l16  = lane & 15;
    const int lhi  = lane >> 4;

    f32x4 acc[4][4];
#pragma unroll
    for (int i = 0; i < 4; ++i)
#pragma unroll
        for (int j = 0; j < 4; ++j)
#pragma unroll
            for (int r = 0; r < 4; ++r) acc[i][j][r] = 0.f;

    const int srow0 = tid >> 2;          // staging row, call 0
    const int sks   = (tid & 3) << 3;    // k element offset (8 bf16 = 16B)
    const int ldsb0 = tid * 16;          // linear LDS byte dest, call 0

    const int kBeg = blockIdx.z * Ksplit;
    const int kEnd = kBeg + Ksplit;

    for (int k0 = kBeg; k0 < kEnd; k0 += 32) {
        __syncthreads();   // LDS reuse guard
#pragma unroll
        for (int call = 0; call < 2; ++call) {
            const int row = srow0 + call * 64;
            const int wb  = ldsb0 + call * 4096;
            const size_t aoff = (size_t)(bm + row) * Ktot + k0 + sks;
            const size_t boff = (size_t)(bn + row) * Ktot + k0 + sks;
            GLOAD_LDS16(Ah + aoff, (char*)Ash + wb);
            GLOAD_LDS16(Al + aoff, (char*)Asl + wb);
            GLOAD_LDS16(Bh + boff, (char*)Bsh + wb);
            GLOAD_LDS16(Bl + boff, (char*)Bsl + wb);
        }
        __syncthreads();   // compiler drains vmcnt before barrier

        bf16x8 ah[4], al[4], bh[4], bl[4];
#pragma unroll
        for (int f = 0; f < 4; ++f) {
            const int ar = (wr + f * 16 + l16) * 32 + lhi * 8;
            const int br = (wc + f * 16 + l16) * 32 + lhi * 8;
            ah[f] = *(const bf16x8*)&Ash[ar];
            al[f] = *(const bf16x8*)&Asl[ar];
            bh[f] = *(const bf16x8*)&Bsh[br];
            bl[f] = *(const bf16x8*)&Bsl[br];
        }
#pragma unroll
        for (int fm = 0; fm < 4; ++fm)
#pragma unroll
            for (int fn = 0; fn < 4; ++fn) {
                acc[fm][fn] = __builtin_amdgcn_mfma_f32_16x16x32_bf16(
                    ah[fm], bh[fn], acc[fm][fn], 0, 0, 0);
                acc[fm][fn] = __builtin_amdgcn_mfma_f32_16x16x32_bf16(
                    al[fm], bh[fn], acc[fm][fn], 0, 0, 0);
                acc[fm][fn] = __builtin_amdgcn_mfma_f32_16x16x32_bf16(
                    ah[fm], bl[fn], acc[fm][fn], 0, 0, 0);
            }
    }

    float* Cp = (EPI == 0) ? (C + (size_t)blockIdx.z * partStride) : C;

    // epilogue: D col = lane&15, row = (lane>>4)*4 + reg  [m89-verified]
#pragma unroll
    for (int fm = 0; fm < 4; ++fm) {
        const int row0 = bm + wr + fm * 16 + lhi * 4;
#pragma unroll
        for (int fn = 0; fn < 4; ++fn) {
            const int col = bn + wc + fn * 16 + l16;
#pragma unroll
            for (int r = 0; r < 4; ++r) {
                const float v = acc[fm][fn][r];
                const size_t m = row0 + r;
                if (EPI == 0) {
                    Cp[m * ldc + col] = v;
                } else {
                    if (col < 2048) C[m * 2048 + col] = v;
                    else            C2[m * 2048 + (col - 2048)] = v;
                }
            }
        }
    }
}

// ---------------------------------------------------------------------------
// Tiled fp32 NT-GEMM (small GEMMs).  EPI 0: plain.  EPI 2: bias + softplus.
// ---------------------------------------------------------------------------
template<int EPI>
__global__ __launch_bounds__(256) void gemm_nt(
    const float* __restrict__ A, const float* __restrict__ B,
    float* __restrict__ C, const float* __restrict__ bias,
    int N, int K, int lda, int ldb, int ldc)
{
    __shared__ float As[16][68];
    __shared__ float Bs[16][68];

    const int tid = threadIdx.x;
    const int tx = tid & 15;
    const int ty = tid >> 4;
    const int bm = blockIdx.x * 64;
    const int bn = blockIdx.y * 64;

    const int r  = tid >> 2;
    const int kc = (tid & 3) << 2;

    float acc[4][4];
#pragma unroll
    for (int i = 0; i < 4; ++i)
#pragma unroll
        for (int j = 0; j < 4; ++j) acc[i][j] = 0.f;

    for (int k0 = 0; k0 < K; k0 += 16) {
        float4 av = *(const float4*)(A + (size_t)(bm + r) * lda + k0 + kc);
        const int cB = bn + r;
        float4 bv = make_float4(0.f, 0.f, 0.f, 0.f);
        if (cB < N) bv = *(const float4*)(B + (size_t)cB * ldb + k0 + kc);

        As[kc + 0][r] = av.x; As[kc + 1][r] = av.y;
        As[kc + 2][r] = av.z; As[kc + 3][r] = av.w;
        Bs[kc + 0][r] = bv.x; Bs[kc + 1][r] = bv.y;
        Bs[kc + 2][r] = bv.z; Bs[kc + 3][r] = bv.w;
        __syncthreads();

#pragma unroll
        for (int kk = 0; kk < 16; ++kk) {
            float4 a4 = *(const float4*)&As[kk][ty << 2];
            float4 b4 = *(const float4*)&Bs[kk][tx << 2];
            float a[4] = {a4.x, a4.y, a4.z, a4.w};
            float b[4] = {b4.x, b4.y, b4.z, b4.w};
#pragma unroll
            for (int i = 0; i < 4; ++i)
#pragma unroll
                for (int j = 0; j < 4; ++j)
                    acc[i][j] = fmaf(a[i], b[j], acc[i][j]);
        }
        __syncthreads();
    }

#pragma unroll
    for (int i = 0; i < 4; ++i) {
        const int m = bm + (ty << 2) + i;
#pragma unroll
        for (int j = 0; j < 4; ++j) {
            const int n = bn + (tx << 2) + j;
            float v = acc[i][j];
            if (EPI == 0) {
                if (n < N) C[(size_t)m * ldc + n] = v;
            } else {
                v += bias[n];
                v = (v > 20.f) ? v : log1pf(expf(v));
                C[(size_t)m * ldc + n] = v;
            }
        }
    }
}

// ---------------------------------------------------------------------------
// Depthwise causal conv (width 4) + bias + SiLU, 4 channels per thread.
// ---------------------------------------------------------------------------
__global__ __launch_bounds__(256) void conv_silu4(
    const float* __restrict__ xin, const float* __restrict__ w,
    const float* __restrict__ bias, float* __restrict__ xout,
    int L, int D)
{
    const long long e4 = (long long)blockIdx.x * 256 + threadIdx.x;
    const int Dq = D >> 2;
    const int dq = (int)(e4 % Dq);
    const long long bl = e4 / Dq;
    const int l = (int)(bl % L);
    const int d = dq << 2;
    const long long base = bl * D + d;

    const float4 zero = make_float4(0.f, 0.f, 0.f, 0.f);
    const float4 x0 = *(const float4*)&xin[base];
    const float4 x1 = (l >= 1) ? *(const float4*)&xin[base - D]     : zero;
    const float4 x2 = (l >= 2) ? *(const float4*)&xin[base - 2*D]   : zero;
    const float4 x3 = (l >= 3) ? *(const float4*)&xin[base - 3*D]   : zero;
    const float4 bv = *(const float4*)&bias[d];

    float4 out;
    {
        const float4 wv = *(const float4*)&w[(d + 0) * 4];
        float acc = bv.x;
        acc = fmaf(wv.w, x0.x, acc); acc = fmaf(wv.z, x1.x, acc);
        acc = fmaf(wv.y, x2.x, acc); acc = fmaf(wv.x, x3.x, acc);
        out.x = acc / (1.f + __expf(-acc));
    }
    {
        const float4 wv = *(const float4*)&w[(d + 1) * 4];
        float acc = bv.y;
        acc = fmaf(wv.w, x0.y, acc); acc = fmaf(wv.z, x1.y, acc);
        acc = fmaf(wv.y, x2.y, acc); acc = fmaf(wv.x, x3.y, acc);
        out.y = acc / (1.f + __expf(-acc));
    }
    {
        const float4 wv = *(const float4*)&w[(d + 2) * 4];
        float acc = bv.z;
        acc = fmaf(wv.w, x0.z, acc); acc = fmaf(wv.z, x1.z, acc);
        acc = fmaf(wv.y, x2.z, acc); acc = fmaf(wv.x, x3.z, acc);
        out.z = acc / (1.f + __expf(-acc));
    }
    {
        const float4 wv = *(const float4*)&w[(d + 3) * 4];
        float acc = bv.w;
        acc = fmaf(wv.w, x0.w, acc); acc = fmaf(wv.z, x1.w, acc);
        acc = fmaf(wv.y, x2.w, acc); acc = fmaf(wv.x, x3.w, acc);
        out.w = acc / (1.f + __expf(-acc));
    }
    *(float4*)&xout[base] = out;
}

// ---------------------------------------------------------------------------
// Scan pass 1 (per-channel): thread owns channel d, 16 states in registers.
// ---------------------------------------------------------------------------
__global__ __launch_bounds__(256) void scan_local2(
    const float* __restrict__ xconv, const float* __restrict__ dt,
    const float* __restrict__ xdbl,  const float* __restrict__ A_log,
    float* __restrict__ Sbuf, float* __restrict__ Pbuf)
{
    __shared__ float Bs[CH][16];

    const int d = blockIdx.x * 256 + threadIdx.x;
    const int c = blockIdx.y;
    const int b = blockIdx.z;
    const long long rowBase = (long long)b * 4096 + (long long)c * CH;

#pragma unroll
    for (int k = 0; k < 2; ++k) {
        const int e = k * 256 + threadIdx.x;
        const int i = e >> 2, j = (e & 3) << 2;
        *(float4*)&Bs[i][j] = *(const float4*)&xdbl[(rowBase + i) * 96 + 64 + j];
    }
    __syncthreads();

    float a[16], S[16];
#pragma unroll
    for (int n = 0; n < 16; ++n) {
        a[n] = -__expf(A_log[d * 16 + n]);
        S[n] = 0.f;
    }
    float sumdt = 0.f;

    for (int i = 0; i < CH; ++i) {
        const long long row = rowBase + i;
        const float dtv = dt[row * 2048 + d];
        const float xv  = xconv[row * 2048 + d];
        const float u   = dtv * xv;
        sumdt += dtv;
#pragma unroll
        for (int n = 0; n < 16; ++n) {
            const float dA = __expf(dtv * a[n]);
            S[n] = fmaf(S[n], dA, u * Bs[i][n]);
        }
    }

    const size_t base = ((((size_t)b * NC + c) * 2048) + d) * 16;
#pragma unroll
    for (int k = 0; k < 4; ++k) {
        *(float4*)&Sbuf[base + k * 4] =
            make_float4(S[k*4], S[k*4+1], S[k*4+2], S[k*4+3]);
        *(float4*)&Pbuf[base + k * 4] =
            make_float4(__expf(sumdt * a[k*4]),   __expf(sumdt * a[k*4+1]),
                        __expf(sumdt * a[k*4+2]), __expf(sumdt * a[k*4+3]));
    }
}

// ---------------------------------------------------------------------------
// Pass 2: sequential prefix over chunks; Sbuf becomes chunk-entering state.
// ---------------------------------------------------------------------------
__global__ __launch_bounds__(256) void scan_chunk_prefix(
    float* __restrict__ Sbuf, const float* __restrict__ Pbuf)
{
    const int tid = blockIdx.x * 256 + threadIdx.x;
    const int b  = tid >> 15;
    const int dn = tid & 32767;

    float H = 0.f;
    for (int c = 0; c < NC; ++c) {
        const size_t idx = ((size_t)b * NC + c) * 32768 + dn;
        const float S = Sbuf[idx];
        const float P = Pbuf[idx];
        Sbuf[idx] = H;
        H = fmaf(P, H, S);
    }
}

// ---------------------------------------------------------------------------
// Scan pass 3 (per-channel): seeded with H, gate, fp32 y in-place to xconv.
// ---------------------------------------------------------------------------
__global__ __launch_bounds__(256) void scan_final2(
    const float* __restrict__ xconv, const float* __restrict__ dt,
    const float* __restrict__ xdbl,  const float* __restrict__ A_log,
    const float* __restrict__ Dp,    const float* __restrict__ z,
    const float* __restrict__ Hbuf,  float* __restrict__ y)
{
    __shared__ float BCs[CH][32];    // [l][0..15]=B, [l][16..31]=C

    const int d = blockIdx.x * 256 + threadIdx.x;
    const int c = blockIdx.y;
    const int b = blockIdx.z;
    const long long rowBase = (long long)b * 4096 + (long long)c * CH;

#pragma unroll
    for (int k = 0; k < 4; ++k) {
        const int e = k * 256 + threadIdx.x;
        const int i = e >> 3, j = (e & 7) << 2;
        *(float4*)&BCs[i][j] = *(const float4*)&xdbl[(rowBase + i) * 96 + 64 + j];
    }
    __syncthreads();

    float a[16], h[16];
    const size_t hbase = ((((size_t)b * NC + c) * 2048) + d) * 16;
#pragma unroll
    for (int k = 0; k < 4; ++k) {
        const float4 hv = *(const float4*)&Hbuf[hbase + k * 4];
        h[k*4] = hv.x; h[k*4+1] = hv.y; h[k*4+2] = hv.z; h[k*4+3] = hv.w;
    }
#pragma unroll
    for (int n = 0; n < 16; ++n) a[n] = -__expf(A_log[d * 16 + n]);
    const float Dv = Dp[d];

    for (int i = 0; i < CH; ++i) {
        const long long row = rowBase + i;
        const float dtv = dt[row * 2048 + d];
        const float xv  = xconv[row * 2048 + d];
        const float u   = dtv * xv;
        float acc = 0.f;
#pragma unroll
        for (int n = 0; n < 16; ++n) {
            const float dA = __expf(dtv * a[n]);
            h[n] = fmaf(h[n], dA, u * BCs[i][n]);
            acc  = fmaf(h[n], BCs[i][16 + n], acc);
        }
        const float zv = z[row * 2048 + d];
        float yv = acc + xv * Dv;
        yv = yv * (zv / (1.f + __expf(-zv)));
        y[row * 2048 + d] = yv;
    }
}

// ---------------------------------------------------------------------------
extern "C" void kernel_launch(void* const* d_in, const int* in_sizes, int n_in,
                              void* d_out, int out_size, void* d_ws, size_t ws_size,
                              hipStream_t stream)
{
    const float* hidden     = (const float*)d_in[0];
    const float* in_proj_w  = (const float*)d_in[1];
    const float* conv_w     = (const float*)d_in[2];
    const float* conv_b     = (const float*)d_in[3];
    const float* x_proj_w   = (const float*)d_in[4];
    const float* dt_proj_w  = (const float*)d_in[5];
    const float* dt_proj_b  = (const float*)d_in[6];
    const float* A_log      = (const float*)d_in[7];
    const float* Dvec       = (const float*)d_in[8];
    const float* out_proj_w = (const float*)d_in[9];
    float* out = (float*)d_out;

    const int L = 4096, dinner = 2048, dmodel = 1024;
    const int M = 2 * L;  // 8192

    // ---- workspace layout: EXACTLY R2's proven 221.25 MB footprint ----
    float* z     = (float*)d_ws;                       // M*2048 fp32
    float* xraw  = z     + (size_t)M * dinner;         // M*2048 (x, dt, then y-pair)
    float* xconv = xraw  + (size_t)M * dinner;         // M*2048 (hid-pair, xconv/y, partials)
    float* xdbl  = xconv + (size_t)M * dinner;         // M*96
    float* Sbuf  = xdbl  + (size_t)M * 96;             // 2*NC*2048*16
    float* Pbuf  = Sbuf  + (size_t)2 * NC * dinner * 16;

    // lifetime-disjoint aliases:
    bf16_t* w1_h  = (bf16_t*)Sbuf;                     // dead before scan
    bf16_t* w1_l  = w1_h + (size_t)2 * dinner * dmodel;
    bf16_t* hid_h = (bf16_t*)xconv;                    // dead at conv
    bf16_t* hid_l = hid_h + (size_t)M * dmodel;
    bf16_t* y_h   = (bf16_t*)xraw;                     // written after dt dead
    bf16_t* y_l   = y_h + (size_t)M * dinner;
    bf16_t* w2_h  = (bf16_t*)z;                        // split after scan uses z
    bf16_t* w2_l  = w2_h + (size_t)dmodel * dinner;
    float*  part  = xconv;                             // out_proj partials (2x)

    // ---- 0. pre-splits for in_proj ----
    split_hl<<<(2 * dinner * dmodel / 4 + 255) / 256, 256, 0, stream>>>(
        in_proj_w, w1_h, w1_l, 2 * dinner * dmodel / 4);
    split_hl<<<(M * dmodel / 4 + 255) / 256, 256, 0, stream>>>(
        hidden, hid_h, hid_l, M * dmodel / 4);

    // ---- 1. in_proj (all-bf16 MFMA): (8192x1024)x(4096x1024)^T -> x | z ----
    gemm_mfma3p<1><<<dim3(M / 128, 4096 / 128, 1), 256, 0, stream>>>(
        hid_h, hid_l, w1_h, w1_l, xraw, z, 4096, dmodel, dmodel, 0, 0);

    // ---- 2. depthwise conv + bias + SiLU (x4 vectorized) ----
    conv_silu4<<<(M * (long long)dinner / 4) / 256, 256, 0, stream>>>(
        xraw, conv_w, conv_b, xconv, L, dinner);

    // ---- 3. x_proj (fp32): (8192x2048)x(96x2048)^T -> xdbl ----
    gemm_nt<0><<<dim3(M / 64, 2), 256, 0, stream>>>(
        xconv, x_proj_w, xdbl, nullptr, 96, 2048, 2048, 2048, 96);

    // ---- 4. dt_proj (fp32): (8192x64)x(2048x64)^T + bias, softplus -> dt ----
    gemm_nt<2><<<dim3(M / 64, 2048 / 64), 256, 0, stream>>>(
        xdbl, dt_proj_w, xraw, dt_proj_b, 2048, 64, 96, 64, 2048);

    // ---- 5. chunked selective scan (per-channel register-state form) ----
    scan_local2<<<dim3(dinner / 256, NC, 2), 256, 0, stream>>>(
        xconv, xraw, xdbl, A_log, Sbuf, Pbuf);
    scan_chunk_prefix<<<256, 256, 0, stream>>>(Sbuf, Pbuf);
    scan_final2<<<dim3(dinner / 256, NC, 2), 256, 0, stream>>>(
        xconv, xraw, xdbl, A_log, Dvec, z, Sbuf, xconv);

    // ---- 5b. post-scan splits: y (over dead dt) and w2 (over dead z) ----
    split_hl<<<(M * dinner / 4 + 255) / 256, 256, 0, stream>>>(
        xconv, y_h, y_l, M * dinner / 4);
    split_hl<<<(dmodel * dinner / 4 + 255) / 256, 256, 0, stream>>>(
        out_proj_w, w2_h, w2_l, dmodel * dinner / 4);

    // ---- 6. out_proj (all-bf16 MFMA, split-K=2): partials then reduce ----
    gemm_mfma3p<0><<<dim3(M / 128, 1024 / 128, 2), 256, 0, stream>>>(
        y_h, y_l, w2_h, w2_l, part, nullptr, 1024, dinner, dinner / 2, 1024,
        (size_t)M * 1024);
    add2<<<(M * dmodel / 4 + 255) / 256, 256, 0, stream>>>(
        part, part + (size_t)M * 1024, out, M * dmodel / 4);
}

// Round 7
// 808.975 us; speedup vs baseline: 1.0119x; 1.0119x over previous
//
#include <hip/hip_runtime.h>
#include <cmath>

#define CH 128          // scan chunk length
#define NC 32           // 4096 / CH

typedef __bf16 bf16_t;
typedef __attribute__((ext_vector_type(8))) __bf16 bf16x8;
typedef __attribute__((ext_vector_type(4))) __bf16 bf16x4;
typedef __attribute__((ext_vector_type(4))) float f32x4;

// CK idiom: generic->AS1/AS3 via uintptr for global_load_lds (width 16).
#define GLOAD_LDS16(gp, lp)                                                     \
    __builtin_amdgcn_global_load_lds(                                           \
        (const __attribute__((address_space(1))) unsigned int*)(uintptr_t)(gp), \
        (__attribute__((address_space(3))) unsigned int*)(uintptr_t)(lp),       \
        16, 0, 0)

// ---------------------------------------------------------------------------
// fp32 -> (hi, lo) bf16 split.  4 floats per thread.
// ---------------------------------------------------------------------------
__global__ __launch_bounds__(256) void split_hl(
    const float* __restrict__ in, bf16_t* __restrict__ hi,
    bf16_t* __restrict__ lo, int n4)
{
    const int i = blockIdx.x * 256 + threadIdx.x;
    if (i >= n4) return;
    const float4 v = ((const float4*)in)[i];
    const bf16_t h0 = (bf16_t)v.x, h1 = (bf16_t)v.y,
                 h2 = (bf16_t)v.z, h3 = (bf16_t)v.w;
    bf16x4 hv = {h0, h1, h2, h3};
    bf16x4 lv = {(bf16_t)(v.x - (float)h0), (bf16_t)(v.y - (float)h1),
                 (bf16_t)(v.z - (float)h2), (bf16_t)(v.w - (float)h3)};
    ((bf16x4*)hi)[i] = hv;
    ((bf16x4*)lo)[i] = lv;
}

// ---------------------------------------------------------------------------
// float4 add of 2 partials:  o = a + b   (out_proj split-K reduce)
// ---------------------------------------------------------------------------
__global__ __launch_bounds__(256) void add2(
    const float* __restrict__ a, const float* __restrict__ b,
    float* __restrict__ o, int n4)
{
    const int i = blockIdx.x * 256 + threadIdx.x;
    if (i >= n4) return;
    const float4 va = ((const float4*)a)[i];
    const float4 vb = ((const float4*)b)[i];
    ((float4*)o)[i] = make_float4(va.x + vb.x, va.y + vb.y,
                                  va.z + vb.z, va.w + vb.w);
}

// ---------------------------------------------------------------------------
// float4 add of 8 partials (x_proj split-K reduce).  stride4 in float4 units.
// ---------------------------------------------------------------------------
__global__ __launch_bounds__(256) void add8(
    const float* __restrict__ p, float* __restrict__ o,
    int n4, size_t stride4)
{
    const int i = blockIdx.x * 256 + threadIdx.x;
    if (i >= n4) return;
    float4 s = make_float4(0.f, 0.f, 0.f, 0.f);
#pragma unroll
    for (int k = 0; k < 8; ++k) {
        const float4 v = ((const float4*)p)[(size_t)k * stride4 + i];
        s.x += v.x; s.y += v.y; s.z += v.z; s.w += v.w;
    }
    ((float4*)o)[i] = s;
}

// ---------------------------------------------------------------------------
// Split-precision MFMA NT-GEMM, all-bf16 staging:
//   C = Ah.Bh^T + Al.Bh^T + Ah.Bl^T      (A fp32 ~= Ah + Al)
// 128x128 tile, BK=32, 4 waves, 4x4 frags mfma_f32_16x16x32_bf16,
// 48 MFMA / k-step, 8x global_load_lds width-16 staging, 32 KB LDS.
// blockIdx.z selects a K-split window.
// EPI 0: (C + z*partStride)[m*ldc+n] = v     (split-K partial store)
// EPI 1: n<2048 -> C (x half), else -> C2 (z half)
// ---------------------------------------------------------------------------
template<int EPI>
__global__ __launch_bounds__(256) void gemm_mfma3p(
    const bf16_t* __restrict__ Ah, const bf16_t* __restrict__ Al,
    const bf16_t* __restrict__ Bh, const bf16_t* __restrict__ Bl,
    float* __restrict__ C, float* __restrict__ C2,
    int N, int Ktot, int Ksplit, int ldc, size_t partStride)
{
    __shared__ __align__(16) bf16_t Ash[128 * 32];
    __shared__ __align__(16) bf16_t Asl[128 * 32];
    __shared__ __align__(16) bf16_t Bsh[128 * 32];
    __shared__ __align__(16) bf16_t Bsl[128 * 32];

    const int tid  = threadIdx.x;
    const int lane = tid & 63;
    const int w    = tid >> 6;
    const int wr   = (w >> 1) * 64;
    const int wc   = (w & 1) * 64;
    const int bm   = blockIdx.x * 128;
    const int bn   = blockIdx.y * 128;
    const int l16  = lane & 15;
    const int lhi  = lane >> 4;

    f32x4 acc[4][4];
#pragma unroll
    for (int i = 0; i < 4; ++i)
#pragma unroll
        for (int j = 0; j < 4; ++j)
#pragma unroll
            for (int r = 0; r < 4; ++r) acc[i][j][r] = 0.f;

    const int srow0 = tid >> 2;          // staging row, call 0
    const int sks   = (tid & 3) << 3;    // k element offset (8 bf16 = 16B)
    const int ldsb0 = tid * 16;          // linear LDS byte dest, call 0

    const int kBeg = blockIdx.z * Ksplit;
    const int kEnd = kBeg + Ksplit;

    for (int k0 = kBeg; k0 < kEnd; k0 += 32) {
        __syncthreads();   // LDS reuse guard
#pragma unroll
        for (int call = 0; call < 2; ++call) {
            const int row = srow0 + call * 64;
            const int wb  = ldsb0 + call * 4096;
            const size_t aoff = (size_t)(bm + row) * Ktot + k0 + sks;
            const size_t boff = (size_t)(bn + row) * Ktot + k0 + sks;
            GLOAD_LDS16(Ah + aoff, (char*)Ash + wb);
            GLOAD_LDS16(Al + aoff, (char*)Asl + wb);
            GLOAD_LDS16(Bh + boff, (char*)Bsh + wb);
            GLOAD_LDS16(Bl + boff, (char*)Bsl + wb);
        }
        __syncthreads();   // compiler drains vmcnt before barrier

        bf16x8 ah[4], al[4], bh[4], bl[4];
#pragma unroll
        for (int f = 0; f < 4; ++f) {
            const int ar = (wr + f * 16 + l16) * 32 + lhi * 8;
            const int br = (wc + f * 16 + l16) * 32 + lhi * 8;
            ah[f] = *(const bf16x8*)&Ash[ar];
            al[f] = *(const bf16x8*)&Asl[ar];
            bh[f] = *(const bf16x8*)&Bsh[br];
            bl[f] = *(const bf16x8*)&Bsl[br];
        }
#pragma unroll
        for (int fm = 0; fm < 4; ++fm)
#pragma unroll
            for (int fn = 0; fn < 4; ++fn) {
                acc[fm][fn] = __builtin_amdgcn_mfma_f32_16x16x32_bf16(
                    ah[fm], bh[fn], acc[fm][fn], 0, 0, 0);
                acc[fm][fn] = __builtin_amdgcn_mfma_f32_16x16x32_bf16(
                    al[fm], bh[fn], acc[fm][fn], 0, 0, 0);
                acc[fm][fn] = __builtin_amdgcn_mfma_f32_16x16x32_bf16(
                    ah[fm], bl[fn], acc[fm][fn], 0, 0, 0);
            }
    }

    float* Cp = (EPI == 0) ? (C + (size_t)blockIdx.z * partStride) : C;

    // epilogue: D col = lane&15, row = (lane>>4)*4 + reg  [m89-verified]
#pragma unroll
    for (int fm = 0; fm < 4; ++fm) {
        const int row0 = bm + wr + fm * 16 + lhi * 4;
#pragma unroll
        for (int fn = 0; fn < 4; ++fn) {
            const int col = bn + wc + fn * 16 + l16;
#pragma unroll
            for (int r = 0; r < 4; ++r) {
                const float v = acc[fm][fn][r];
                const size_t m = row0 + r;
                if (EPI == 0) {
                    Cp[m * ldc + col] = v;
                } else {
                    if (col < 2048) C[m * 2048 + col] = v;
                    else            C2[m * 2048 + (col - 2048)] = v;
                }
            }
        }
    }
}

// ---------------------------------------------------------------------------
// Tiled fp32 NT-GEMM with split-K (x_proj).  64x64 tile, K-window per
// blockIdx.z, partial stored at C + z*partStride.
// ---------------------------------------------------------------------------
__global__ __launch_bounds__(256) void gemm_nt_sk(
    const float* __restrict__ A, const float* __restrict__ B,
    float* __restrict__ C,
    int N, int Ksplit, int lda, int ldb, int ldc, size_t partStride)
{
    __shared__ float As[16][68];
    __shared__ float Bs[16][68];

    const int tid = threadIdx.x;
    const int tx = tid & 15;
    const int ty = tid >> 4;
    const int bm = blockIdx.x * 64;
    const int bn = blockIdx.y * 64;

    const int r  = tid >> 2;
    const int kc = (tid & 3) << 2;

    float acc[4][4];
#pragma unroll
    for (int i = 0; i < 4; ++i)
#pragma unroll
        for (int j = 0; j < 4; ++j) acc[i][j] = 0.f;

    const int kBeg = blockIdx.z * Ksplit;
    const int kEnd = kBeg + Ksplit;

    for (int k0 = kBeg; k0 < kEnd; k0 += 16) {
        float4 av = *(const float4*)(A + (size_t)(bm + r) * lda + k0 + kc);
        const int cB = bn + r;
        float4 bv = make_float4(0.f, 0.f, 0.f, 0.f);
        if (cB < N) bv = *(const float4*)(B + (size_t)cB * ldb + k0 + kc);

        As[kc + 0][r] = av.x; As[kc + 1][r] = av.y;
        As[kc + 2][r] = av.z; As[kc + 3][r] = av.w;
        Bs[kc + 0][r] = bv.x; Bs[kc + 1][r] = bv.y;
        Bs[kc + 2][r] = bv.z; Bs[kc + 3][r] = bv.w;
        __syncthreads();

#pragma unroll
        for (int kk = 0; kk < 16; ++kk) {
            float4 a4 = *(const float4*)&As[kk][ty << 2];
            float4 b4 = *(const float4*)&Bs[kk][tx << 2];
            float a[4] = {a4.x, a4.y, a4.z, a4.w};
            float b[4] = {b4.x, b4.y, b4.z, b4.w};
#pragma unroll
            for (int i = 0; i < 4; ++i)
#pragma unroll
                for (int j = 0; j < 4; ++j)
                    acc[i][j] = fmaf(a[i], b[j], acc[i][j]);
        }
        __syncthreads();
    }

    float* Cp = C + (size_t)blockIdx.z * partStride;
#pragma unroll
    for (int i = 0; i < 4; ++i) {
        const int m = bm + (ty << 2) + i;
#pragma unroll
        for (int j = 0; j < 4; ++j) {
            const int n = bn + (tx << 2) + j;
            if (n < N) Cp[(size_t)m * ldc + n] = acc[i][j];
        }
    }
}

// ---------------------------------------------------------------------------
// dt_proj, B-resident: dt = softplus(xdbl[:, 0:64] @ W^T + bias)
// W [2048][64].  Block: 128 cols x 256 rows; B-chunk fully staged in LDS
// (pad 65 -> conflict-free), A rows staged 16 at a time.
// ---------------------------------------------------------------------------
__global__ __launch_bounds__(256) void dt_proj_br(
    const float* __restrict__ xdbl, const float* __restrict__ W,
    const float* __restrict__ bias, float* __restrict__ dt)
{
    __shared__ float Bsh[128][65];
    __shared__ float Ash[16][64];

    const int tid  = threadIdx.x;
    const int n0   = blockIdx.x * 128;
    const int r0   = blockIdx.y * 256;
    const int half = tid >> 7;           // wave-uniform (waves 0,1 / 2,3)
    const int col  = tid & 127;

    // stage B chunk: 128 rows x 64 k; thread t loads 8 float4
    {
        const int f0 = tid * 8;
#pragma unroll
        for (int q = 0; q < 8; ++q) {
            const int f = f0 + q;
            const int rr = f >> 4;
            const int k4 = (f & 15) << 2;
            const float4 v = *(const float4*)&W[(size_t)(n0 + rr) * 64 + k4];
            Bsh[rr][k4+0]=v.x; Bsh[rr][k4+1]=v.y;
            Bsh[rr][k4+2]=v.z; Bsh[rr][k4+3]=v.w;
        }
    }
    const float bv = bias[n0 + col];
    __syncthreads();

    for (int round = 0; round < 16; ++round) {
        // stage 16 A rows (8 for each half): 256 float4
        {
            const int rr = tid >> 4;                 // 0..15
            const int k4 = (tid & 15) << 2;
            const int gr = r0 + (rr >> 3) * 128 + round * 8 + (rr & 7);
            const float4 v = *(const float4*)&xdbl[(size_t)gr * 96 + k4];
            Ash[rr][k4+0]=v.x; Ash[rr][k4+1]=v.y;
            Ash[rr][k4+2]=v.z; Ash[rr][k4+3]=v.w;
        }
        __syncthreads();
#pragma unroll
        for (int rr = 0; rr < 8; ++rr) {
            float acc = bv;
            const float* arow = Ash[half * 8 + rr];
            const float* bcol = Bsh[col];
#pragma unroll
            for (int k = 0; k < 64; ++k)
                acc = fmaf(arow[k], bcol[k], acc);
            const int grow = r0 + half * 128 + round * 8 + rr;
            const float sp = (acc > 20.f) ? acc : log1pf(expf(acc));
            dt[(size_t)grow * 2048 + n0 + col] = sp;
        }
        __syncthreads();
    }
}

// ---------------------------------------------------------------------------
// Depthwise causal conv (width 4) + bias + SiLU, 4 channels per thread.
// ---------------------------------------------------------------------------
__global__ __launch_bounds__(256) void conv_silu4(
    const float* __restrict__ xin, const float* __restrict__ w,
    const float* __restrict__ bias, float* __restrict__ xout,
    int L, int D)
{
    const long long e4 = (long long)blockIdx.x * 256 + threadIdx.x;
    const int Dq = D >> 2;
    const int dq = (int)(e4 % Dq);
    const long long bl = e4 / Dq;
    const int l = (int)(bl % L);
    const int d = dq << 2;
    const long long base = bl * D + d;

    const float4 zero = make_float4(0.f, 0.f, 0.f, 0.f);
    const float4 x0 = *(const float4*)&xin[base];
    const float4 x1 = (l >= 1) ? *(const float4*)&xin[base - D]     : zero;
    const float4 x2 = (l >= 2) ? *(const float4*)&xin[base - 2*D]   : zero;
    const float4 x3 = (l >= 3) ? *(const float4*)&xin[base - 3*D]   : zero;
    const float4 bv = *(const float4*)&bias[d];

    float4 out;
    {
        const float4 wv = *(const float4*)&w[(d + 0) * 4];
        float acc = bv.x;
        acc = fmaf(wv.w, x0.x, acc); acc = fmaf(wv.z, x1.x, acc);
        acc = fmaf(wv.y, x2.x, acc); acc = fmaf(wv.x, x3.x, acc);
        out.x = acc / (1.f + __expf(-acc));
    }
    {
        const float4 wv = *(const float4*)&w[(d + 1) * 4];
        float acc = bv.y;
        acc = fmaf(wv.w, x0.y, acc); acc = fmaf(wv.z, x1.y, acc);
        acc = fmaf(wv.y, x2.y, acc); acc = fmaf(wv.x, x3.y, acc);
        out.y = acc / (1.f + __expf(-acc));
    }
    {
        const float4 wv = *(const float4*)&w[(d + 2) * 4];
        float acc = bv.z;
        acc = fmaf(wv.w, x0.z, acc); acc = fmaf(wv.z, x1.z, acc);
        acc = fmaf(wv.y, x2.z, acc); acc = fmaf(wv.x, x3.z, acc);
        out.z = acc / (1.f + __expf(-acc));
    }
    {
        const float4 wv = *(const float4*)&w[(d + 3) * 4];
        float acc = bv.w;
        acc = fmaf(wv.w, x0.w, acc); acc = fmaf(wv.z, x1.w, acc);
        acc = fmaf(wv.y, x2.w, acc); acc = fmaf(wv.x, x3.w, acc);
        out.w = acc / (1.f + __expf(-acc));
    }
    *(float4*)&xout[base] = out;
}

// ---------------------------------------------------------------------------
// Scan pass 1 (per-channel): thread owns channel d, 16 states in registers.
// ---------------------------------------------------------------------------
__global__ __launch_bounds__(256) void scan_local2(
    const float* __restrict__ xconv, const float* __restrict__ dt,
    const float* __restrict__ xdbl,  const float* __restrict__ A_log,
    float* __restrict__ Sbuf, float* __restrict__ Pbuf)
{
    __shared__ float Bs[CH][16];

    const int d = blockIdx.x * 256 + threadIdx.x;
    const int c = blockIdx.y;
    const int b = blockIdx.z;
    const long long rowBase = (long long)b * 4096 + (long long)c * CH;

#pragma unroll
    for (int k = 0; k < 2; ++k) {
        const int e = k * 256 + threadIdx.x;
        const int i = e >> 2, j = (e & 3) << 2;
        *(float4*)&Bs[i][j] = *(const float4*)&xdbl[(rowBase + i) * 96 + 64 + j];
    }
    __syncthreads();

    float a[16], S[16];
#pragma unroll
    for (int n = 0; n < 16; ++n) {
        a[n] = -__expf(A_log[d * 16 + n]);
        S[n] = 0.f;
    }
    float sumdt = 0.f;

    for (int i = 0; i < CH; ++i) {
        const long long row = rowBase + i;
        const float dtv = dt[row * 2048 + d];
        const float xv  = xconv[row * 2048 + d];
        const float u   = dtv * xv;
        sumdt += dtv;
#pragma unroll
        for (int n = 0; n < 16; ++n) {
            const float dA = __expf(dtv * a[n]);
            S[n] = fmaf(S[n], dA, u * Bs[i][n]);
        }
    }

    const size_t base = ((((size_t)b * NC + c) * 2048) + d) * 16;
#pragma unroll
    for (int k = 0; k < 4; ++k) {
        *(float4*)&Sbuf[base + k * 4] =
            make_float4(S[k*4], S[k*4+1], S[k*4+2], S[k*4+3]);
        *(float4*)&Pbuf[base + k * 4] =
            make_float4(__expf(sumdt * a[k*4]),   __expf(sumdt * a[k*4+1]),
                        __expf(sumdt * a[k*4+2]), __expf(sumdt * a[k*4+3]));
    }
}

// ---------------------------------------------------------------------------
// Pass 2: sequential prefix over chunks; Sbuf becomes chunk-entering state.
// ---------------------------------------------------------------------------
__global__ __launch_bounds__(256) void scan_chunk_prefix(
    float* __restrict__ Sbuf, const float* __restrict__ Pbuf)
{
    const int tid = blockIdx.x * 256 + threadIdx.x;
    const int b  = tid >> 15;
    const int dn = tid & 32767;

    float H = 0.f;
    for (int c = 0; c < NC; ++c) {
        const size_t idx = ((size_t)b * NC + c) * 32768 + dn;
        const float S = Sbuf[idx];
        const float P = Pbuf[idx];
        Sbuf[idx] = H;
        H = fmaf(P, H, S);
    }
}

// ---------------------------------------------------------------------------
// Scan pass 3 (per-channel): seeded with H, gate, fp32 y in-place to xconv.
// ---------------------------------------------------------------------------
__global__ __launch_bounds__(256) void scan_final2(
    const float* __restrict__ xconv, const float* __restrict__ dt,
    const float* __restrict__ xdbl,  const float* __restrict__ A_log,
    const float* __restrict__ Dp,    const float* __restrict__ z,
    const float* __restrict__ Hbuf,  float* __restrict__ y)
{
    __shared__ float BCs[CH][32];    // [l][0..15]=B, [l][16..31]=C

    const int d = blockIdx.x * 256 + threadIdx.x;
    const int c = blockIdx.y;
    const int b = blockIdx.z;
    const long long rowBase = (long long)b * 4096 + (long long)c * CH;

#pragma unroll
    for (int k = 0; k < 4; ++k) {
        const int e = k * 256 + threadIdx.x;
        const int i = e >> 3, j = (e & 7) << 2;
        *(float4*)&BCs[i][j] = *(const float4*)&xdbl[(rowBase + i) * 96 + 64 + j];
    }
    __syncthreads();

    float a[16], h[16];
    const size_t hbase = ((((size_t)b * NC + c) * 2048) + d) * 16;
#pragma unroll
    for (int k = 0; k < 4; ++k) {
        const float4 hv = *(const float4*)&Hbuf[hbase + k * 4];
        h[k*4] = hv.x; h[k*4+1] = hv.y; h[k*4+2] = hv.z; h[k*4+3] = hv.w;
    }
#pragma unroll
    for (int n = 0; n < 16; ++n) a[n] = -__expf(A_log[d * 16 + n]);
    const float Dv = Dp[d];

    for (int i = 0; i < CH; ++i) {
        const long long row = rowBase + i;
        const float dtv = dt[row * 2048 + d];
        const float xv  = xconv[row * 2048 + d];
        const float u   = dtv * xv;
        float acc = 0.f;
#pragma unroll
        for (int n = 0; n < 16; ++n) {
            const float dA = __expf(dtv * a[n]);
            h[n] = fmaf(h[n], dA, u * BCs[i][n]);
            acc  = fmaf(h[n], BCs[i][16 + n], acc);
        }
        const float zv = z[row * 2048 + d];
        float yv = acc + xv * Dv;
        yv = yv * (zv / (1.f + __expf(-zv)));
        y[row * 2048 + d] = yv;
    }
}

// ---------------------------------------------------------------------------
extern "C" void kernel_launch(void* const* d_in, const int* in_sizes, int n_in,
                              void* d_out, int out_size, void* d_ws, size_t ws_size,
                              hipStream_t stream)
{
    const float* hidden     = (const float*)d_in[0];
    const float* in_proj_w  = (const float*)d_in[1];
    const float* conv_w     = (const float*)d_in[2];
    const float* conv_b     = (const float*)d_in[3];
    const float* x_proj_w   = (const float*)d_in[4];
    const float* dt_proj_w  = (const float*)d_in[5];
    const float* dt_proj_b  = (const float*)d_in[6];
    const float* A_log      = (const float*)d_in[7];
    const float* Dvec       = (const float*)d_in[8];
    const float* out_proj_w = (const float*)d_in[9];
    float* out = (float*)d_out;

    const int L = 4096, dinner = 2048, dmodel = 1024;
    const int M = 2 * L;  // 8192

    // ---- workspace layout: EXACTLY R2's proven 221.25 MB footprint ----
    float* z     = (float*)d_ws;                       // M*2048 fp32
    float* xraw  = z     + (size_t)M * dinner;         // M*2048 (x, xproj parts, dt, y-pair)
    float* xconv = xraw  + (size_t)M * dinner;         // M*2048 (hid-pair, xconv/y, partials)
    float* xdbl  = xconv + (size_t)M * dinner;         // M*96
    float* Sbuf  = xdbl  + (size_t)M * 96;             // 2*NC*2048*16
    float* Pbuf  = Sbuf  + (size_t)2 * NC * dinner * 16;

    // lifetime-disjoint aliases:
    bf16_t* w1_h  = (bf16_t*)Sbuf;                     // dead before scan
    bf16_t* w1_l  = w1_h + (size_t)2 * dinner * dmodel;
    bf16_t* hid_h = (bf16_t*)xconv;                    // dead at conv write
    bf16_t* hid_l = hid_h + (size_t)M * dmodel;
    float*  xp_part = xraw;                            // x_proj partials (25MB, xraw dead post-conv)
    bf16_t* y_h   = (bf16_t*)xraw;                     // written after dt dead
    bf16_t* y_l   = y_h + (size_t)M * dinner;
    bf16_t* w2_h  = (bf16_t*)z;                        // split after scan uses z
    bf16_t* w2_l  = w2_h + (size_t)dmodel * dinner;
    float*  part  = xconv;                             // out_proj partials (2x 33.5MB)

    // ---- 0. pre-splits for in_proj ----
    split_hl<<<(2 * dinner * dmodel / 4 + 255) / 256, 256, 0, stream>>>(
        in_proj_w, w1_h, w1_l, 2 * dinner * dmodel / 4);
    split_hl<<<(M * dmodel / 4 + 255) / 256, 256, 0, stream>>>(
        hidden, hid_h, hid_l, M * dmodel / 4);

    // ---- 1. in_proj (all-bf16 MFMA): (8192x1024)x(4096x1024)^T -> x | z ----
    gemm_mfma3p<1><<<dim3(M / 128, 4096 / 128, 1), 256, 0, stream>>>(
        hid_h, hid_l, w1_h, w1_l, xraw, z, 4096, dmodel, dmodel, 0, 0);

    // ---- 2. depthwise conv + bias + SiLU (x4 vectorized) ----
    conv_silu4<<<(M * (long long)dinner / 4) / 256, 256, 0, stream>>>(
        xraw, conv_w, conv_b, xconv, L, dinner);

    // ---- 3. x_proj (fp32, split-K=8): partials -> add8 -> xdbl ----
    gemm_nt_sk<<<dim3(M / 64, 2, 8), 256, 0, stream>>>(
        xconv, x_proj_w, xp_part, 96, 2048 / 8, 2048, 2048, 96,
        (size_t)M * 96);
    add8<<<(M * 96 / 4 + 255) / 256, 256, 0, stream>>>(
        xp_part, xdbl, M * 96 / 4, (size_t)M * 96 / 4);

    // ---- 4. dt_proj (B-resident): softplus(xdbl[:,0:64] @ W^T + b) -> dt ----
    dt_proj_br<<<dim3(2048 / 128, M / 256), 256, 0, stream>>>(
        xdbl, dt_proj_w, dt_proj_b, xraw);

    // ---- 5. chunked selective scan (per-channel register-state form) ----
    scan_local2<<<dim3(dinner / 256, NC, 2), 256, 0, stream>>>(
        xconv, xraw, xdbl, A_log, Sbuf, Pbuf);
    scan_chunk_prefix<<<256, 256, 0, stream>>>(Sbuf, Pbuf);
    scan_final2<<<dim3(dinner / 256, NC, 2), 256, 0, stream>>>(
        xconv, xraw, xdbl, A_log, Dvec, z, Sbuf, xconv);

    // ---- 5b. post-scan splits: y (over dead dt) and w2 (over dead z) ----
    split_hl<<<(M * dinner / 4 + 255) / 256, 256, 0, stream>>>(
        xconv, y_h, y_l, M * dinner / 4);
    split_hl<<<(dmodel * dinner / 4 + 255) / 256, 256, 0, stream>>>(
        out_proj_w, w2_h, w2_l, dmodel * dinner / 4);

    // ---- 6. out_proj (all-bf16 MFMA, split-K=2): partials then reduce ----
    gemm_mfma3p<0><<<dim3(M / 128, 1024 / 128, 2), 256, 0, stream>>>(
        y_h, y_l, w2_h, w2_l, part, nullptr, 1024, dinner, dinner / 2, 1024,
        (size_t)M * 1024);
    add2<<<(M * dmodel / 4 + 255) / 256, 256, 0, stream>>>(
        part, part + (size_t)M * 1024, out, M * dmodel / 4);
}

// Round 8
// 778.162 us; speedup vs baseline: 1.0520x; 1.0396x over previous
//
#include <hip/hip_runtime.h>
#include <cmath>

#define CH 128          // scan chunk length
#define NC 32           // 4096 / CH

typedef __bf16 bf16_t;
typedef __attribute__((ext_vector_type(8))) __bf16 bf16x8;
typedef __attribute__((ext_vector_type(4))) __bf16 bf16x4;
typedef __attribute__((ext_vector_type(4))) float f32x4;

// CK idiom: generic->AS1/AS3 via uintptr for global_load_lds (width 16).
#define GLOAD_LDS16(gp, lp)                                                     \
    __builtin_amdgcn_global_load_lds(                                           \
        (const __attribute__((address_space(1))) unsigned int*)(uintptr_t)(gp), \
        (__attribute__((address_space(3))) unsigned int*)(uintptr_t)(lp),       \
        16, 0, 0)

// ---------------------------------------------------------------------------
// fp32 -> (hi, lo) bf16 split.  4 floats per thread.
// ---------------------------------------------------------------------------
__global__ __launch_bounds__(256) void split_hl(
    const float* __restrict__ in, bf16_t* __restrict__ hi,
    bf16_t* __restrict__ lo, int n4)
{
    const int i = blockIdx.x * 256 + threadIdx.x;
    if (i >= n4) return;
    const float4 v = ((const float4*)in)[i];
    const bf16_t h0 = (bf16_t)v.x, h1 = (bf16_t)v.y,
                 h2 = (bf16_t)v.z, h3 = (bf16_t)v.w;
    bf16x4 hv = {h0, h1, h2, h3};
    bf16x4 lv = {(bf16_t)(v.x - (float)h0), (bf16_t)(v.y - (float)h1),
                 (bf16_t)(v.z - (float)h2), (bf16_t)(v.w - (float)h3)};
    ((bf16x4*)hi)[i] = hv;
    ((bf16x4*)lo)[i] = lv;
}

// ---------------------------------------------------------------------------
// float4 add of 8 partials (x_proj split-K reduce).  stride4 in float4 units.
// ---------------------------------------------------------------------------
__global__ __launch_bounds__(256) void add8(
    const float* __restrict__ p, float* __restrict__ o,
    int n4, size_t stride4)
{
    const int i = blockIdx.x * 256 + threadIdx.x;
    if (i >= n4) return;
    float4 s = make_float4(0.f, 0.f, 0.f, 0.f);
#pragma unroll
    for (int k = 0; k < 8; ++k) {
        const float4 v = ((const float4*)p)[(size_t)k * stride4 + i];
        s.x += v.x; s.y += v.y; s.z += v.z; s.w += v.w;
    }
    ((float4*)o)[i] = s;
}

// ---------------------------------------------------------------------------
// Split-precision MFMA NT-GEMM, all-bf16 staging (in_proj):
//   C = Ah.Bh^T + Al.Bh^T + Ah.Bl^T      (A fp32 ~= Ah + Al)
// 128x128 tile, BK=32, 4 waves, 4x4 frags mfma_f32_16x16x32_bf16,
// 48 MFMA / k-step, 8x global_load_lds width-16 staging, 32 KB LDS.
// EPI 1: n<2048 -> C (x half), else -> C2 (z half)
// ---------------------------------------------------------------------------
template<int EPI>
__global__ __launch_bounds__(256) void gemm_mfma3p(
    const bf16_t* __restrict__ Ah, const bf16_t* __restrict__ Al,
    const bf16_t* __restrict__ Bh, const bf16_t* __restrict__ Bl,
    float* __restrict__ C, float* __restrict__ C2,
    int N, int Ktot, int Ksplit, int ldc, size_t partStride)
{
    __shared__ __align__(16) bf16_t Ash[128 * 32];
    __shared__ __align__(16) bf16_t Asl[128 * 32];
    __shared__ __align__(16) bf16_t Bsh[128 * 32];
    __shared__ __align__(16) bf16_t Bsl[128 * 32];

    const int tid  = threadIdx.x;
    const int lane = tid & 63;
    const int w    = tid >> 6;
    const int wr   = (w >> 1) * 64;
    const int wc   = (w & 1) * 64;
    const int bm   = blockIdx.x * 128;
    const int bn   = blockIdx.y * 128;
    const int l16  = lane & 15;
    const int lhi  = lane >> 4;

    f32x4 acc[4][4];
#pragma unroll
    for (int i = 0; i < 4; ++i)
#pragma unroll
        for (int j = 0; j < 4; ++j)
#pragma unroll
            for (int r = 0; r < 4; ++r) acc[i][j][r] = 0.f;

    const int srow0 = tid >> 2;          // staging row, call 0
    const int sks   = (tid & 3) << 3;    // k element offset (8 bf16 = 16B)
    const int ldsb0 = tid * 16;          // linear LDS byte dest, call 0

    const int kBeg = blockIdx.z * Ksplit;
    const int kEnd = kBeg + Ksplit;

    for (int k0 = kBeg; k0 < kEnd; k0 += 32) {
        __syncthreads();   // LDS reuse guard
#pragma unroll
        for (int call = 0; call < 2; ++call) {
            const int row = srow0 + call * 64;
            const int wb  = ldsb0 + call * 4096;
            const size_t aoff = (size_t)(bm + row) * Ktot + k0 + sks;
            const size_t boff = (size_t)(bn + row) * Ktot + k0 + sks;
            GLOAD_LDS16(Ah + aoff, (char*)Ash + wb);
            GLOAD_LDS16(Al + aoff, (char*)Asl + wb);
            GLOAD_LDS16(Bh + boff, (char*)Bsh + wb);
            GLOAD_LDS16(Bl + boff, (char*)Bsl + wb);
        }
        __syncthreads();   // compiler drains vmcnt before barrier

        bf16x8 ah[4], al[4], bh[4], bl[4];
#pragma unroll
        for (int f = 0; f < 4; ++f) {
            const int ar = (wr + f * 16 + l16) * 32 + lhi * 8;
            const int br = (wc + f * 16 + l16) * 32 + lhi * 8;
            ah[f] = *(const bf16x8*)&Ash[ar];
            al[f] = *(const bf16x8*)&Asl[ar];
            bh[f] = *(const bf16x8*)&Bsh[br];
            bl[f] = *(const bf16x8*)&Bsl[br];
        }
#pragma unroll
        for (int fm = 0; fm < 4; ++fm)
#pragma unroll
            for (int fn = 0; fn < 4; ++fn) {
                acc[fm][fn] = __builtin_amdgcn_mfma_f32_16x16x32_bf16(
                    ah[fm], bh[fn], acc[fm][fn], 0, 0, 0);
                acc[fm][fn] = __builtin_amdgcn_mfma_f32_16x16x32_bf16(
                    al[fm], bh[fn], acc[fm][fn], 0, 0, 0);
                acc[fm][fn] = __builtin_amdgcn_mfma_f32_16x16x32_bf16(
                    ah[fm], bl[fn], acc[fm][fn], 0, 0, 0);
            }
    }

    float* Cp = (EPI == 0) ? (C + (size_t)blockIdx.z * partStride) : C;

    // epilogue: D col = lane&15, row = (lane>>4)*4 + reg  [m89-verified]
#pragma unroll
    for (int fm = 0; fm < 4; ++fm) {
        const int row0 = bm + wr + fm * 16 + lhi * 4;
#pragma unroll
        for (int fn = 0; fn < 4; ++fn) {
            const int col = bn + wc + fn * 16 + l16;
#pragma unroll
            for (int r = 0; r < 4; ++r) {
                const float v = acc[fm][fn][r];
                const size_t m = row0 + r;
                if (EPI == 0) {
                    Cp[m * ldc + col] = v;
                } else {
                    if (col < 2048) C[m * 2048 + col] = v;
                    else            C2[m * 2048 + (col - 2048)] = v;
                }
            }
        }
    }
}

// ---------------------------------------------------------------------------
// out_proj GEMM: C = A.B^T, A [M][K] fp32 reg-staged (split to bf16 hi/lo
// in-kernel -> LDS), B pre-split bf16 pair via global_load_lds.
// 64x128 tile, BK=32, 4 waves (2x2, each 32x64), 2x4 frags, 24 MFMA/k-step.
// Direct store to C (no split-K).
// ---------------------------------------------------------------------------
__global__ __launch_bounds__(256) void gemm_mfma3o(
    const float* __restrict__ A,
    const bf16_t* __restrict__ Bh, const bf16_t* __restrict__ Bl,
    float* __restrict__ C, int K, int ldc)
{
    __shared__ __align__(16) bf16_t Ash[64 * 32];
    __shared__ __align__(16) bf16_t Asl[64 * 32];
    __shared__ __align__(16) bf16_t Bsh[128 * 32];
    __shared__ __align__(16) bf16_t Bsl[128 * 32];

    const int tid  = threadIdx.x;
    const int lane = tid & 63;
    const int w    = tid >> 6;
    const int wr   = (w >> 1) * 32;     // 2 wave-rows of 32
    const int wc   = (w & 1) * 64;      // 2 wave-cols of 64
    const int bm   = blockIdx.x * 64;
    const int bn   = blockIdx.y * 128;
    const int l16  = lane & 15;
    const int lhi  = lane >> 4;

    f32x4 acc[2][4];
#pragma unroll
    for (int i = 0; i < 2; ++i)
#pragma unroll
        for (int j = 0; j < 4; ++j)
#pragma unroll
            for (int r = 0; r < 4; ++r) acc[i][j][r] = 0.f;

    const int srowA = tid >> 2;          // 0..63
    const int sks   = (tid & 3) << 3;    // k element offset (8 elems)
    const int ldsb0 = tid * 16;

    for (int k0 = 0; k0 < K; k0 += 32) {
        __syncthreads();   // LDS reuse guard
        // B: 128 rows, 2 gload calls per half
#pragma unroll
        for (int call = 0; call < 2; ++call) {
            const int row = srowA + call * 64;
            const int wb  = ldsb0 + call * 4096;
            const size_t boff = (size_t)(bn + row) * K + k0 + sks;
            GLOAD_LDS16(Bh + boff, (char*)Bsh + wb);
            GLOAD_LDS16(Bl + boff, (char*)Bsl + wb);
        }
        // A: 64 rows fp32, reg-stage + split
        {
            const float* ap = A + (size_t)(bm + srowA) * K + k0 + sks;
            const float4 v0 = *(const float4*)ap;
            const float4 v1 = *(const float4*)(ap + 4);
            const float fv[8] = {v0.x, v0.y, v0.z, v0.w, v1.x, v1.y, v1.z, v1.w};
            bf16x8 hv, lv;
#pragma unroll
            for (int e = 0; e < 8; ++e) {
                const bf16_t h = (bf16_t)fv[e];
                hv[e] = h;
                lv[e] = (bf16_t)(fv[e] - (float)h);
            }
            *(bf16x8*)((char*)Ash + ldsb0) = hv;
            *(bf16x8*)((char*)Asl + ldsb0) = lv;
        }
        __syncthreads();   // drains vmcnt (B) + lgkmcnt (A)

        bf16x8 ah[2], al[2], bh[4], bl[4];
#pragma unroll
        for (int f = 0; f < 2; ++f) {
            const int ar = (wr + f * 16 + l16) * 32 + lhi * 8;
            ah[f] = *(const bf16x8*)&Ash[ar];
            al[f] = *(const bf16x8*)&Asl[ar];
        }
#pragma unroll
        for (int f = 0; f < 4; ++f) {
            const int br = (wc + f * 16 + l16) * 32 + lhi * 8;
            bh[f] = *(const bf16x8*)&Bsh[br];
            bl[f] = *(const bf16x8*)&Bsl[br];
        }
#pragma unroll
        for (int fm = 0; fm < 2; ++fm)
#pragma unroll
            for (int fn = 0; fn < 4; ++fn) {
                acc[fm][fn] = __builtin_amdgcn_mfma_f32_16x16x32_bf16(
                    ah[fm], bh[fn], acc[fm][fn], 0, 0, 0);
                acc[fm][fn] = __builtin_amdgcn_mfma_f32_16x16x32_bf16(
                    al[fm], bh[fn], acc[fm][fn], 0, 0, 0);
                acc[fm][fn] = __builtin_amdgcn_mfma_f32_16x16x32_bf16(
                    ah[fm], bl[fn], acc[fm][fn], 0, 0, 0);
            }
    }

    // epilogue
#pragma unroll
    for (int fm = 0; fm < 2; ++fm) {
        const int row0 = bm + wr + fm * 16 + lhi * 4;
#pragma unroll
        for (int fn = 0; fn < 4; ++fn) {
            const int col = bn + wc + fn * 16 + l16;
#pragma unroll
            for (int r = 0; r < 4; ++r)
                C[(size_t)(row0 + r) * ldc + col] = acc[fm][fn][r];
        }
    }
}

// ---------------------------------------------------------------------------
// Tiled fp32 NT-GEMM with split-K (x_proj).  64x64 tile.
// ---------------------------------------------------------------------------
__global__ __launch_bounds__(256) void gemm_nt_sk(
    const float* __restrict__ A, const float* __restrict__ B,
    float* __restrict__ C,
    int N, int Ksplit, int lda, int ldb, int ldc, size_t partStride)
{
    __shared__ float As[16][68];
    __shared__ float Bs[16][68];

    const int tid = threadIdx.x;
    const int tx = tid & 15;
    const int ty = tid >> 4;
    const int bm = blockIdx.x * 64;
    const int bn = blockIdx.y * 64;

    const int r  = tid >> 2;
    const int kc = (tid & 3) << 2;

    float acc[4][4];
#pragma unroll
    for (int i = 0; i < 4; ++i)
#pragma unroll
        for (int j = 0; j < 4; ++j) acc[i][j] = 0.f;

    const int kBeg = blockIdx.z * Ksplit;
    const int kEnd = kBeg + Ksplit;

    for (int k0 = kBeg; k0 < kEnd; k0 += 16) {
        float4 av = *(const float4*)(A + (size_t)(bm + r) * lda + k0 + kc);
        const int cB = bn + r;
        float4 bv = make_float4(0.f, 0.f, 0.f, 0.f);
        if (cB < N) bv = *(const float4*)(B + (size_t)cB * ldb + k0 + kc);

        As[kc + 0][r] = av.x; As[kc + 1][r] = av.y;
        As[kc + 2][r] = av.z; As[kc + 3][r] = av.w;
        Bs[kc + 0][r] = bv.x; Bs[kc + 1][r] = bv.y;
        Bs[kc + 2][r] = bv.z; Bs[kc + 3][r] = bv.w;
        __syncthreads();

#pragma unroll
        for (int kk = 0; kk < 16; ++kk) {
            float4 a4 = *(const float4*)&As[kk][ty << 2];
            float4 b4 = *(const float4*)&Bs[kk][tx << 2];
            float a[4] = {a4.x, a4.y, a4.z, a4.w};
            float b[4] = {b4.x, b4.y, b4.z, b4.w};
#pragma unroll
            for (int i = 0; i < 4; ++i)
#pragma unroll
                for (int j = 0; j < 4; ++j)
                    acc[i][j] = fmaf(a[i], b[j], acc[i][j]);
        }
        __syncthreads();
    }

    float* Cp = C + (size_t)blockIdx.z * partStride;
#pragma unroll
    for (int i = 0; i < 4; ++i) {
        const int m = bm + (ty << 2) + i;
#pragma unroll
        for (int j = 0; j < 4; ++j) {
            const int n = bn + (tx << 2) + j;
            if (n < N) Cp[(size_t)m * ldc + n] = acc[i][j];
        }
    }
}

// ---------------------------------------------------------------------------
// dt_proj, B-resident: dt = softplus(xdbl[:, 0:64] @ W^T + bias)
// ---------------------------------------------------------------------------
__global__ __launch_bounds__(256) void dt_proj_br(
    const float* __restrict__ xdbl, const float* __restrict__ W,
    const float* __restrict__ bias, float* __restrict__ dt)
{
    __shared__ float Bsh[128][65];
    __shared__ float Ash[16][64];

    const int tid  = threadIdx.x;
    const int n0   = blockIdx.x * 128;
    const int r0   = blockIdx.y * 256;
    const int half = tid >> 7;
    const int col  = tid & 127;

    {
        const int f0 = tid * 8;
#pragma unroll
        for (int q = 0; q < 8; ++q) {
            const int f = f0 + q;
            const int rr = f >> 4;
            const int k4 = (f & 15) << 2;
            const float4 v = *(const float4*)&W[(size_t)(n0 + rr) * 64 + k4];
            Bsh[rr][k4+0]=v.x; Bsh[rr][k4+1]=v.y;
            Bsh[rr][k4+2]=v.z; Bsh[rr][k4+3]=v.w;
        }
    }
    const float bv = bias[n0 + col];
    __syncthreads();

    for (int round = 0; round < 16; ++round) {
        {
            const int rr = tid >> 4;
            const int k4 = (tid & 15) << 2;
            const int gr = r0 + (rr >> 3) * 128 + round * 8 + (rr & 7);
            const float4 v = *(const float4*)&xdbl[(size_t)gr * 96 + k4];
            Ash[rr][k4+0]=v.x; Ash[rr][k4+1]=v.y;
            Ash[rr][k4+2]=v.z; Ash[rr][k4+3]=v.w;
        }
        __syncthreads();
#pragma unroll
        for (int rr = 0; rr < 8; ++rr) {
            float acc = bv;
            const float* arow = Ash[half * 8 + rr];
            const float* bcol = Bsh[col];
#pragma unroll
            for (int k = 0; k < 64; ++k)
                acc = fmaf(arow[k], bcol[k], acc);
            const int grow = r0 + half * 128 + round * 8 + rr;
            const float sp = (acc > 20.f) ? acc : log1pf(expf(acc));
            dt[(size_t)grow * 2048 + n0 + col] = sp;
        }
        __syncthreads();
    }
}

// ---------------------------------------------------------------------------
// Depthwise causal conv (width 4) + bias + SiLU, 4 channels per thread.
// ---------------------------------------------------------------------------
__global__ __launch_bounds__(256) void conv_silu4(
    const float* __restrict__ xin, const float* __restrict__ w,
    const float* __restrict__ bias, float* __restrict__ xout,
    int L, int D)
{
    const long long e4 = (long long)blockIdx.x * 256 + threadIdx.x;
    const int Dq = D >> 2;
    const int dq = (int)(e4 % Dq);
    const long long bl = e4 / Dq;
    const int l = (int)(bl % L);
    const int d = dq << 2;
    const long long base = bl * D + d;

    const float4 zero = make_float4(0.f, 0.f, 0.f, 0.f);
    const float4 x0 = *(const float4*)&xin[base];
    const float4 x1 = (l >= 1) ? *(const float4*)&xin[base - D]     : zero;
    const float4 x2 = (l >= 2) ? *(const float4*)&xin[base - 2*D]   : zero;
    const float4 x3 = (l >= 3) ? *(const float4*)&xin[base - 3*D]   : zero;
    const float4 bv = *(const float4*)&bias[d];

    float4 out;
    {
        const float4 wv = *(const float4*)&w[(d + 0) * 4];
        float acc = bv.x;
        acc = fmaf(wv.w, x0.x, acc); acc = fmaf(wv.z, x1.x, acc);
        acc = fmaf(wv.y, x2.x, acc); acc = fmaf(wv.x, x3.x, acc);
        out.x = acc / (1.f + __expf(-acc));
    }
    {
        const float4 wv = *(const float4*)&w[(d + 1) * 4];
        float acc = bv.y;
        acc = fmaf(wv.w, x0.y, acc); acc = fmaf(wv.z, x1.y, acc);
        acc = fmaf(wv.y, x2.y, acc); acc = fmaf(wv.x, x3.y, acc);
        out.y = acc / (1.f + __expf(-acc));
    }
    {
        const float4 wv = *(const float4*)&w[(d + 2) * 4];
        float acc = bv.z;
        acc = fmaf(wv.w, x0.z, acc); acc = fmaf(wv.z, x1.z, acc);
        acc = fmaf(wv.y, x2.z, acc); acc = fmaf(wv.x, x3.z, acc);
        out.z = acc / (1.f + __expf(-acc));
    }
    {
        const float4 wv = *(const float4*)&w[(d + 3) * 4];
        float acc = bv.w;
        acc = fmaf(wv.w, x0.w, acc); acc = fmaf(wv.z, x1.w, acc);
        acc = fmaf(wv.y, x2.w, acc); acc = fmaf(wv.x, x3.w, acc);
        out.w = acc / (1.f + __expf(-acc));
    }
    *(float4*)&xout[base] = out;
}

// ---------------------------------------------------------------------------
// Scan pass 1 (per-channel): thread owns channel d, 16 states in registers.
// ---------------------------------------------------------------------------
__global__ __launch_bounds__(256) void scan_local2(
    const float* __restrict__ xconv, const float* __restrict__ dt,
    const float* __restrict__ xdbl,  const float* __restrict__ A_log,
    float* __restrict__ Sbuf, float* __restrict__ Pbuf)
{
    __shared__ float Bs[CH][16];

    const int d = blockIdx.x * 256 + threadIdx.x;
    const int c = blockIdx.y;
    const int b = blockIdx.z;
    const long long rowBase = (long long)b * 4096 + (long long)c * CH;

#pragma unroll
    for (int k = 0; k < 2; ++k) {
        const int e = k * 256 + threadIdx.x;
        const int i = e >> 2, j = (e & 3) << 2;
        *(float4*)&Bs[i][j] = *(const float4*)&xdbl[(rowBase + i) * 96 + 64 + j];
    }
    __syncthreads();

    float a[16], S[16];
#pragma unroll
    for (int n = 0; n < 16; ++n) {
        a[n] = -__expf(A_log[d * 16 + n]);
        S[n] = 0.f;
    }
    float sumdt = 0.f;

    for (int i = 0; i < CH; ++i) {
        const long long row = rowBase + i;
        const float dtv = dt[row * 2048 + d];
        const float xv  = xconv[row * 2048 + d];
        const float u   = dtv * xv;
        sumdt += dtv;
#pragma unroll
        for (int n = 0; n < 16; ++n) {
            const float dA = __expf(dtv * a[n]);
            S[n] = fmaf(S[n], dA, u * Bs[i][n]);
        }
    }

    const size_t base = ((((size_t)b * NC + c) * 2048) + d) * 16;
#pragma unroll
    for (int k = 0; k < 4; ++k) {
        *(float4*)&Sbuf[base + k * 4] =
            make_float4(S[k*4], S[k*4+1], S[k*4+2], S[k*4+3]);
        *(float4*)&Pbuf[base + k * 4] =
            make_float4(__expf(sumdt * a[k*4]),   __expf(sumdt * a[k*4+1]),
                        __expf(sumdt * a[k*4+2]), __expf(sumdt * a[k*4+3]));
    }
}

// ---------------------------------------------------------------------------
// Pass 2: sequential prefix over chunks; Sbuf becomes chunk-entering state.
// ---------------------------------------------------------------------------
__global__ __launch_bounds__(256) void scan_chunk_prefix(
    float* __restrict__ Sbuf, const float* __restrict__ Pbuf)
{
    const int tid = blockIdx.x * 256 + threadIdx.x;
    const int b  = tid >> 15;
    const int dn = tid & 32767;

    float H = 0.f;
    for (int c = 0; c < NC; ++c) {
        const size_t idx = ((size_t)b * NC + c) * 32768 + dn;
        const float S = Sbuf[idx];
        const float P = Pbuf[idx];
        Sbuf[idx] = H;
        H = fmaf(P, H, S);
    }
}

// ---------------------------------------------------------------------------
// Scan pass 3 (per-channel): seeded with H, gate, fp32 y in-place to xconv.
// ---------------------------------------------------------------------------
__global__ __launch_bounds__(256) void scan_final2(
    const float* __restrict__ xconv, const float* __restrict__ dt,
    const float* __restrict__ xdbl,  const float* __restrict__ A_log,
    const float* __restrict__ Dp,    const float* __restrict__ z,
    const float* __restrict__ Hbuf,  float* __restrict__ y)
{
    __shared__ float BCs[CH][32];    // [l][0..15]=B, [l][16..31]=C

    const int d = blockIdx.x * 256 + threadIdx.x;
    const int c = blockIdx.y;
    const int b = blockIdx.z;
    const long long rowBase = (long long)b * 4096 + (long long)c * CH;

#pragma unroll
    for (int k = 0; k < 4; ++k) {
        const int e = k * 256 + threadIdx.x;
        const int i = e >> 3, j = (e & 7) << 2;
        *(float4*)&BCs[i][j] = *(const float4*)&xdbl[(rowBase + i) * 96 + 64 + j];
    }
    __syncthreads();

    float a[16], h[16];
    const size_t hbase = ((((size_t)b * NC + c) * 2048) + d) * 16;
#pragma unroll
    for (int k = 0; k < 4; ++k) {
        const float4 hv = *(const float4*)&Hbuf[hbase + k * 4];
        h[k*4] = hv.x; h[k*4+1] = hv.y; h[k*4+2] = hv.z; h[k*4+3] = hv.w;
    }
#pragma unroll
    for (int n = 0; n < 16; ++n) a[n] = -__expf(A_log[d * 16 + n]);
    const float Dv = Dp[d];

    for (int i = 0; i < CH; ++i) {
        const long long row = rowBase + i;
        const float dtv = dt[row * 2048 + d];
        const float xv  = xconv[row * 2048 + d];
        const float u   = dtv * xv;
        float acc = 0.f;
#pragma unroll
        for (int n = 0; n < 16; ++n) {
            const float dA = __expf(dtv * a[n]);
            h[n] = fmaf(h[n], dA, u * BCs[i][n]);
            acc  = fmaf(h[n], BCs[i][16 + n], acc);
        }
        const float zv = z[row * 2048 + d];
        float yv = acc + xv * Dv;
        yv = yv * (zv / (1.f + __expf(-zv)));
        y[row * 2048 + d] = yv;
    }
}

// ---------------------------------------------------------------------------
extern "C" void kernel_launch(void* const* d_in, const int* in_sizes, int n_in,
                              void* d_out, int out_size, void* d_ws, size_t ws_size,
                              hipStream_t stream)
{
    const float* hidden     = (const float*)d_in[0];
    const float* in_proj_w  = (const float*)d_in[1];
    const float* conv_w     = (const float*)d_in[2];
    const float* conv_b     = (const float*)d_in[3];
    const float* x_proj_w   = (const float*)d_in[4];
    const float* dt_proj_w  = (const float*)d_in[5];
    const float* dt_proj_b  = (const float*)d_in[6];
    const float* A_log      = (const float*)d_in[7];
    const float* Dvec       = (const float*)d_in[8];
    const float* out_proj_w = (const float*)d_in[9];
    float* out = (float*)d_out;

    const int L = 4096, dinner = 2048, dmodel = 1024;
    const int M = 2 * L;  // 8192

    // ---- workspace layout: EXACTLY R2's proven 221.25 MB footprint ----
    float* z     = (float*)d_ws;                       // M*2048 fp32
    float* xraw  = z     + (size_t)M * dinner;         // M*2048 (x, xproj parts, dt)
    float* xconv = xraw  + (size_t)M * dinner;         // M*2048 (hid-pair, xconv, y)
    float* xdbl  = xconv + (size_t)M * dinner;         // M*96
    float* Sbuf  = xdbl  + (size_t)M * 96;             // 2*NC*2048*16
    float* Pbuf  = Sbuf  + (size_t)2 * NC * dinner * 16;

    // lifetime-disjoint aliases:
    bf16_t* w1_h  = (bf16_t*)Sbuf;                     // dead before scan
    bf16_t* w1_l  = w1_h + (size_t)2 * dinner * dmodel;
    bf16_t* hid_h = (bf16_t*)xconv;                    // dead at conv write
    bf16_t* hid_l = hid_h + (size_t)M * dmodel;
    float*  xp_part = xraw;                            // x_proj partials (xraw dead post-conv)
    bf16_t* w2_h  = (bf16_t*)z;                        // split after scan uses z
    bf16_t* w2_l  = w2_h + (size_t)dmodel * dinner;

    // ---- 0. pre-splits for in_proj ----
    split_hl<<<(2 * dinner * dmodel / 4 + 255) / 256, 256, 0, stream>>>(
        in_proj_w, w1_h, w1_l, 2 * dinner * dmodel / 4);
    split_hl<<<(M * dmodel / 4 + 255) / 256, 256, 0, stream>>>(
        hidden, hid_h, hid_l, M * dmodel / 4);

    // ---- 1. in_proj (all-bf16 MFMA): (8192x1024)x(4096x1024)^T -> x | z ----
    gemm_mfma3p<1><<<dim3(M / 128, 4096 / 128, 1), 256, 0, stream>>>(
        hid_h, hid_l, w1_h, w1_l, xraw, z, 4096, dmodel, dmodel, 0, 0);

    // ---- 2. depthwise conv + bias + SiLU (x4 vectorized) ----
    conv_silu4<<<(M * (long long)dinner / 4) / 256, 256, 0, stream>>>(
        xraw, conv_w, conv_b, xconv, L, dinner);

    // ---- 3. x_proj (fp32, split-K=8): partials -> add8 -> xdbl ----
    gemm_nt_sk<<<dim3(M / 64, 2, 8), 256, 0, stream>>>(
        xconv, x_proj_w, xp_part, 96, 2048 / 8, 2048, 2048, 96,
        (size_t)M * 96);
    add8<<<(M * 96 / 4 + 255) / 256, 256, 0, stream>>>(
        xp_part, xdbl, M * 96 / 4, (size_t)M * 96 / 4);

    // ---- 4. dt_proj (B-resident): softplus(xdbl[:,0:64] @ W^T + b) -> dt ----
    dt_proj_br<<<dim3(2048 / 128, M / 256), 256, 0, stream>>>(
        xdbl, dt_proj_w, dt_proj_b, xraw);

    // ---- 5. chunked selective scan (per-channel register-state form) ----
    scan_local2<<<dim3(dinner / 256, NC, 2), 256, 0, stream>>>(
        xconv, xraw, xdbl, A_log, Sbuf, Pbuf);
    scan_chunk_prefix<<<256, 256, 0, stream>>>(Sbuf, Pbuf);
    scan_final2<<<dim3(dinner / 256, NC, 2), 256, 0, stream>>>(
        xconv, xraw, xdbl, A_log, Dvec, z, Sbuf, xconv);

    // ---- 5b. split out_proj_w into bf16 hi/lo (into z region, now dead) ----
    split_hl<<<(dmodel * dinner / 4 + 255) / 256, 256, 0, stream>>>(
        out_proj_w, w2_h, w2_l, dmodel * dinner / 4);

    // ---- 6. out_proj: A=y fp32 reg-staged, 64x128 tile, direct store ----
    gemm_mfma3o<<<dim3(M / 64, 1024 / 128), 256, 0, stream>>>(
        xconv, w2_h, w2_l, out, dinner, 1024);
}

// Round 9
// 739.665 us; speedup vs baseline: 1.1067x; 1.0520x over previous
//
#include <hip/hip_runtime.h>
#include <cmath>

#define CH 128          // scan chunk length
#define NC 32           // 4096 / CH

typedef __bf16 bf16_t;
typedef __attribute__((ext_vector_type(8))) __bf16 bf16x8;
typedef __attribute__((ext_vector_type(4))) __bf16 bf16x4;
typedef __attribute__((ext_vector_type(4))) float f32x4;

// CK idiom: generic->AS1/AS3 via uintptr for global_load_lds (width 16).
#define GLOAD_LDS16(gp, lp)                                                     \
    __builtin_amdgcn_global_load_lds(                                           \
        (const __attribute__((address_space(1))) unsigned int*)(uintptr_t)(gp), \
        (__attribute__((address_space(3))) unsigned int*)(uintptr_t)(lp),       \
        16, 0, 0)

// ---------------------------------------------------------------------------
// fp32 -> (hi, lo) bf16 split.  4 floats per thread.
// ---------------------------------------------------------------------------
__global__ __launch_bounds__(256) void split_hl(
    const float* __restrict__ in, bf16_t* __restrict__ hi,
    bf16_t* __restrict__ lo, int n4)
{
    const int i = blockIdx.x * 256 + threadIdx.x;
    if (i >= n4) return;
    const float4 v = ((const float4*)in)[i];
    const bf16_t h0 = (bf16_t)v.x, h1 = (bf16_t)v.y,
                 h2 = (bf16_t)v.z, h3 = (bf16_t)v.w;
    bf16x4 hv = {h0, h1, h2, h3};
    bf16x4 lv = {(bf16_t)(v.x - (float)h0), (bf16_t)(v.y - (float)h1),
                 (bf16_t)(v.z - (float)h2), (bf16_t)(v.w - (float)h3)};
    ((bf16x4*)hi)[i] = hv;
    ((bf16x4*)lo)[i] = lv;
}

// ---------------------------------------------------------------------------
// float4 add of 8 partials (x_proj split-K reduce).  stride4 in float4 units.
// ---------------------------------------------------------------------------
__global__ __launch_bounds__(256) void add8(
    const float* __restrict__ p, float* __restrict__ o,
    int n4, size_t stride4)
{
    const int i = blockIdx.x * 256 + threadIdx.x;
    if (i >= n4) return;
    float4 s = make_float4(0.f, 0.f, 0.f, 0.f);
#pragma unroll
    for (int k = 0; k < 8; ++k) {
        const float4 v = ((const float4*)p)[(size_t)k * stride4 + i];
        s.x += v.x; s.y += v.y; s.z += v.z; s.w += v.w;
    }
    ((float4*)o)[i] = s;
}

// ---------------------------------------------------------------------------
// Split-precision MFMA NT-GEMM, all-bf16 staging (in_proj x-half):
//   C = Ah.Bh^T + Al.Bh^T + Ah.Bl^T      (A fp32 ~= Ah + Al)
// 128x128 tile, BK=32, 4 waves, 4x4 frags mfma_f32_16x16x32_bf16,
// 48 MFMA / k-step, 8x global_load_lds width-16 staging, 32 KB LDS.
// EPI 0: (C + z*partStride)[m*ldc+n] = v
// ---------------------------------------------------------------------------
template<int EPI>
__global__ __launch_bounds__(256) void gemm_mfma3p(
    const bf16_t* __restrict__ Ah, const bf16_t* __restrict__ Al,
    const bf16_t* __restrict__ Bh, const bf16_t* __restrict__ Bl,
    float* __restrict__ C, float* __restrict__ C2,
    int N, int Ktot, int Ksplit, int ldc, size_t partStride)
{
    __shared__ __align__(16) bf16_t Ash[128 * 32];
    __shared__ __align__(16) bf16_t Asl[128 * 32];
    __shared__ __align__(16) bf16_t Bsh[128 * 32];
    __shared__ __align__(16) bf16_t Bsl[128 * 32];

    const int tid  = threadIdx.x;
    const int lane = tid & 63;
    const int w    = tid >> 6;
    const int wr   = (w >> 1) * 64;
    const int wc   = (w & 1) * 64;
    const int bm   = blockIdx.x * 128;
    const int bn   = blockIdx.y * 128;
    const int l16  = lane & 15;
    const int lhi  = lane >> 4;

    f32x4 acc[4][4];
#pragma unroll
    for (int i = 0; i < 4; ++i)
#pragma unroll
        for (int j = 0; j < 4; ++j)
#pragma unroll
            for (int r = 0; r < 4; ++r) acc[i][j][r] = 0.f;

    const int srow0 = tid >> 2;          // staging row, call 0
    const int sks   = (tid & 3) << 3;    // k element offset (8 bf16 = 16B)
    const int ldsb0 = tid * 16;          // linear LDS byte dest, call 0

    const int kBeg = blockIdx.z * Ksplit;
    const int kEnd = kBeg + Ksplit;

    for (int k0 = kBeg; k0 < kEnd; k0 += 32) {
        __syncthreads();   // LDS reuse guard
#pragma unroll
        for (int call = 0; call < 2; ++call) {
            const int row = srow0 + call * 64;
            const int wb  = ldsb0 + call * 4096;
            const size_t aoff = (size_t)(bm + row) * Ktot + k0 + sks;
            const size_t boff = (size_t)(bn + row) * Ktot + k0 + sks;
            GLOAD_LDS16(Ah + aoff, (char*)Ash + wb);
            GLOAD_LDS16(Al + aoff, (char*)Asl + wb);
            GLOAD_LDS16(Bh + boff, (char*)Bsh + wb);
            GLOAD_LDS16(Bl + boff, (char*)Bsl + wb);
        }
        __syncthreads();   // compiler drains vmcnt before barrier

        bf16x8 ah[4], al[4], bh[4], bl[4];
#pragma unroll
        for (int f = 0; f < 4; ++f) {
            const int ar = (wr + f * 16 + l16) * 32 + lhi * 8;
            const int br = (wc + f * 16 + l16) * 32 + lhi * 8;
            ah[f] = *(const bf16x8*)&Ash[ar];
            al[f] = *(const bf16x8*)&Asl[ar];
            bh[f] = *(const bf16x8*)&Bsh[br];
            bl[f] = *(const bf16x8*)&Bsl[br];
        }
#pragma unroll
        for (int fm = 0; fm < 4; ++fm)
#pragma unroll
            for (int fn = 0; fn < 4; ++fn) {
                acc[fm][fn] = __builtin_amdgcn_mfma_f32_16x16x32_bf16(
                    ah[fm], bh[fn], acc[fm][fn], 0, 0, 0);
                acc[fm][fn] = __builtin_amdgcn_mfma_f32_16x16x32_bf16(
                    al[fm], bh[fn], acc[fm][fn], 0, 0, 0);
                acc[fm][fn] = __builtin_amdgcn_mfma_f32_16x16x32_bf16(
                    ah[fm], bl[fn], acc[fm][fn], 0, 0, 0);
            }
    }

    float* Cp = (EPI == 0) ? (C + (size_t)blockIdx.z * partStride) : C;

    // epilogue: D col = lane&15, row = (lane>>4)*4 + reg  [m89-verified]
#pragma unroll
    for (int fm = 0; fm < 4; ++fm) {
        const int row0 = bm + wr + fm * 16 + lhi * 4;
#pragma unroll
        for (int fn = 0; fn < 4; ++fn) {
            const int col = bn + wc + fn * 16 + l16;
#pragma unroll
            for (int r = 0; r < 4; ++r) {
                const float v = acc[fm][fn][r];
                const size_t m = row0 + r;
                if (EPI == 0) {
                    Cp[m * ldc + col] = v;
                } else {
                    if (col < 2048) C[m * 2048 + col] = v;
                    else            C2[m * 2048 + (col - 2048)] = v;
                }
            }
        }
    }
}

// ---------------------------------------------------------------------------
// Plain 1-term bf16 MFMA NT-GEMM (in_proj z-half): C = Ah.Bh^T.
// z is only consumed by the SiLU gate -> bf16 rounding error (~1e-3 on z)
// propagates to < ~3e-4 on the final output.  m97 structure: 128x128 tile,
// BK=32, 16 MFMA/k-step, 16 KB LDS.
// ---------------------------------------------------------------------------
__global__ __launch_bounds__(256) void gemm_bf16_1t(
    const bf16_t* __restrict__ Ah, const bf16_t* __restrict__ Bh,
    float* __restrict__ C, int Ktot, int ldc)
{
    __shared__ __align__(16) bf16_t Ash[128 * 32];
    __shared__ __align__(16) bf16_t Bsh[128 * 32];

    const int tid  = threadIdx.x;
    const int lane = tid & 63;
    const int w    = tid >> 6;
    const int wr   = (w >> 1) * 64;
    const int wc   = (w & 1) * 64;
    const int bm   = blockIdx.x * 128;
    const int bn   = blockIdx.y * 128;
    const int l16  = lane & 15;
    const int lhi  = lane >> 4;

    f32x4 acc[4][4];
#pragma unroll
    for (int i = 0; i < 4; ++i)
#pragma unroll
        for (int j = 0; j < 4; ++j)
#pragma unroll
            for (int r = 0; r < 4; ++r) acc[i][j][r] = 0.f;

    const int srow0 = tid >> 2;
    const int sks   = (tid & 3) << 3;
    const int ldsb0 = tid * 16;

    for (int k0 = 0; k0 < Ktot; k0 += 32) {
        __syncthreads();
#pragma unroll
        for (int call = 0; call < 2; ++call) {
            const int row = srow0 + call * 64;
            const int wb  = ldsb0 + call * 4096;
            GLOAD_LDS16(Ah + (size_t)(bm + row) * Ktot + k0 + sks, (char*)Ash + wb);
            GLOAD_LDS16(Bh + (size_t)(bn + row) * Ktot + k0 + sks, (char*)Bsh + wb);
        }
        __syncthreads();

        bf16x8 af[4], bf[4];
#pragma unroll
        for (int f = 0; f < 4; ++f) {
            af[f] = *(const bf16x8*)&Ash[(wr + f * 16 + l16) * 32 + lhi * 8];
            bf[f] = *(const bf16x8*)&Bsh[(wc + f * 16 + l16) * 32 + lhi * 8];
        }
#pragma unroll
        for (int fm = 0; fm < 4; ++fm)
#pragma unroll
            for (int fn = 0; fn < 4; ++fn)
                acc[fm][fn] = __builtin_amdgcn_mfma_f32_16x16x32_bf16(
                    af[fm], bf[fn], acc[fm][fn], 0, 0, 0);
    }

#pragma unroll
    for (int fm = 0; fm < 4; ++fm) {
        const int row0 = bm + wr + fm * 16 + lhi * 4;
#pragma unroll
        for (int fn = 0; fn < 4; ++fn) {
            const int col = bn + wc + fn * 16 + l16;
#pragma unroll
            for (int r = 0; r < 4; ++r)
                C[(size_t)(row0 + r) * ldc + col] = acc[fm][fn][r];
        }
    }
}

// ---------------------------------------------------------------------------
// out_proj GEMM: C = A.B^T, A [M][K] fp32 reg-staged (split to bf16 hi/lo
// in-kernel -> LDS), B pre-split bf16 pair via global_load_lds.
// 64x128 tile, BK=32, 4 waves (2x2, each 32x64), 2x4 frags, 24 MFMA/k-step.
// ---------------------------------------------------------------------------
__global__ __launch_bounds__(256) void gemm_mfma3o(
    const float* __restrict__ A,
    const bf16_t* __restrict__ Bh, const bf16_t* __restrict__ Bl,
    float* __restrict__ C, int K, int ldc)
{
    __shared__ __align__(16) bf16_t Ash[64 * 32];
    __shared__ __align__(16) bf16_t Asl[64 * 32];
    __shared__ __align__(16) bf16_t Bsh[128 * 32];
    __shared__ __align__(16) bf16_t Bsl[128 * 32];

    const int tid  = threadIdx.x;
    const int lane = tid & 63;
    const int w    = tid >> 6;
    const int wr   = (w >> 1) * 32;
    const int wc   = (w & 1) * 64;
    const int bm   = blockIdx.x * 64;
    const int bn   = blockIdx.y * 128;
    const int l16  = lane & 15;
    const int lhi  = lane >> 4;

    f32x4 acc[2][4];
#pragma unroll
    for (int i = 0; i < 2; ++i)
#pragma unroll
        for (int j = 0; j < 4; ++j)
#pragma unroll
            for (int r = 0; r < 4; ++r) acc[i][j][r] = 0.f;

    const int srowA = tid >> 2;
    const int sks   = (tid & 3) << 3;
    const int ldsb0 = tid * 16;

    for (int k0 = 0; k0 < K; k0 += 32) {
        __syncthreads();
#pragma unroll
        for (int call = 0; call < 2; ++call) {
            const int row = srowA + call * 64;
            const int wb  = ldsb0 + call * 4096;
            const size_t boff = (size_t)(bn + row) * K + k0 + sks;
            GLOAD_LDS16(Bh + boff, (char*)Bsh + wb);
            GLOAD_LDS16(Bl + boff, (char*)Bsl + wb);
        }
        {
            const float* ap = A + (size_t)(bm + srowA) * K + k0 + sks;
            const float4 v0 = *(const float4*)ap;
            const float4 v1 = *(const float4*)(ap + 4);
            const float fv[8] = {v0.x, v0.y, v0.z, v0.w, v1.x, v1.y, v1.z, v1.w};
            bf16x8 hv, lv;
#pragma unroll
            for (int e = 0; e < 8; ++e) {
                const bf16_t h = (bf16_t)fv[e];
                hv[e] = h;
                lv[e] = (bf16_t)(fv[e] - (float)h);
            }
            *(bf16x8*)((char*)Ash + ldsb0) = hv;
            *(bf16x8*)((char*)Asl + ldsb0) = lv;
        }
        __syncthreads();

        bf16x8 ah[2], al[2], bh[4], bl[4];
#pragma unroll
        for (int f = 0; f < 2; ++f) {
            const int ar = (wr + f * 16 + l16) * 32 + lhi * 8;
            ah[f] = *(const bf16x8*)&Ash[ar];
            al[f] = *(const bf16x8*)&Asl[ar];
        }
#pragma unroll
        for (int f = 0; f < 4; ++f) {
            const int br = (wc + f * 16 + l16) * 32 + lhi * 8;
            bh[f] = *(const bf16x8*)&Bsh[br];
            bl[f] = *(const bf16x8*)&Bsl[br];
        }
#pragma unroll
        for (int fm = 0; fm < 2; ++fm)
#pragma unroll
            for (int fn = 0; fn < 4; ++fn) {
                acc[fm][fn] = __builtin_amdgcn_mfma_f32_16x16x32_bf16(
                    ah[fm], bh[fn], acc[fm][fn], 0, 0, 0);
                acc[fm][fn] = __builtin_amdgcn_mfma_f32_16x16x32_bf16(
                    al[fm], bh[fn], acc[fm][fn], 0, 0, 0);
                acc[fm][fn] = __builtin_amdgcn_mfma_f32_16x16x32_bf16(
                    ah[fm], bl[fn], acc[fm][fn], 0, 0, 0);
            }
    }

#pragma unroll
    for (int fm = 0; fm < 2; ++fm) {
        const int row0 = bm + wr + fm * 16 + lhi * 4;
#pragma unroll
        for (int fn = 0; fn < 4; ++fn) {
            const int col = bn + wc + fn * 16 + l16;
#pragma unroll
            for (int r = 0; r < 4; ++r)
                C[(size_t)(row0 + r) * ldc + col] = acc[fm][fn][r];
        }
    }
}

// ---------------------------------------------------------------------------
// Tiled fp32 NT-GEMM with split-K (x_proj).  64x64 tile.
// ---------------------------------------------------------------------------
__global__ __launch_bounds__(256) void gemm_nt_sk(
    const float* __restrict__ A, const float* __restrict__ B,
    float* __restrict__ C,
    int N, int Ksplit, int lda, int ldb, int ldc, size_t partStride)
{
    __shared__ float As[16][68];
    __shared__ float Bs[16][68];

    const int tid = threadIdx.x;
    const int tx = tid & 15;
    const int ty = tid >> 4;
    const int bm = blockIdx.x * 64;
    const int bn = blockIdx.y * 64;

    const int r  = tid >> 2;
    const int kc = (tid & 3) << 2;

    float acc[4][4];
#pragma unroll
    for (int i = 0; i < 4; ++i)
#pragma unroll
        for (int j = 0; j < 4; ++j) acc[i][j] = 0.f;

    const int kBeg = blockIdx.z * Ksplit;
    const int kEnd = kBeg + Ksplit;

    for (int k0 = kBeg; k0 < kEnd; k0 += 16) {
        float4 av = *(const float4*)(A + (size_t)(bm + r) * lda + k0 + kc);
        const int cB = bn + r;
        float4 bv = make_float4(0.f, 0.f, 0.f, 0.f);
        if (cB < N) bv = *(const float4*)(B + (size_t)cB * ldb + k0 + kc);

        As[kc + 0][r] = av.x; As[kc + 1][r] = av.y;
        As[kc + 2][r] = av.z; As[kc + 3][r] = av.w;
        Bs[kc + 0][r] = bv.x; Bs[kc + 1][r] = bv.y;
        Bs[kc + 2][r] = bv.z; Bs[kc + 3][r] = bv.w;
        __syncthreads();

#pragma unroll
        for (int kk = 0; kk < 16; ++kk) {
            float4 a4 = *(const float4*)&As[kk][ty << 2];
            float4 b4 = *(const float4*)&Bs[kk][tx << 2];
            float a[4] = {a4.x, a4.y, a4.z, a4.w};
            float b[4] = {b4.x, b4.y, b4.z, b4.w};
#pragma unroll
            for (int i = 0; i < 4; ++i)
#pragma unroll
                for (int j = 0; j < 4; ++j)
                    acc[i][j] = fmaf(a[i], b[j], acc[i][j]);
        }
        __syncthreads();
    }

    float* Cp = C + (size_t)blockIdx.z * partStride;
#pragma unroll
    for (int i = 0; i < 4; ++i) {
        const int m = bm + (ty << 2) + i;
#pragma unroll
        for (int j = 0; j < 4; ++j) {
            const int n = bn + (tx << 2) + j;
            if (n < N) Cp[(size_t)m * ldc + n] = acc[i][j];
        }
    }
}

// ---------------------------------------------------------------------------
// dt_proj, B-resident: dt = softplus(xdbl[:, 0:64] @ W^T + bias)
// ---------------------------------------------------------------------------
__global__ __launch_bounds__(256) void dt_proj_br(
    const float* __restrict__ xdbl, const float* __restrict__ W,
    const float* __restrict__ bias, float* __restrict__ dt)
{
    __shared__ float Bsh[128][65];
    __shared__ float Ash[16][64];

    const int tid  = threadIdx.x;
    const int n0   = blockIdx.x * 128;
    const int r0   = blockIdx.y * 256;
    const int half = tid >> 7;
    const int col  = tid & 127;

    {
        const int f0 = tid * 8;
#pragma unroll
        for (int q = 0; q < 8; ++q) {
            const int f = f0 + q;
            const int rr = f >> 4;
            const int k4 = (f & 15) << 2;
            const float4 v = *(const float4*)&W[(size_t)(n0 + rr) * 64 + k4];
            Bsh[rr][k4+0]=v.x; Bsh[rr][k4+1]=v.y;
            Bsh[rr][k4+2]=v.z; Bsh[rr][k4+3]=v.w;
        }
    }
    const float bv = bias[n0 + col];
    __syncthreads();

    for (int round = 0; round < 16; ++round) {
        {
            const int rr = tid >> 4;
            const int k4 = (tid & 15) << 2;
            const int gr = r0 + (rr >> 3) * 128 + round * 8 + (rr & 7);
            const float4 v = *(const float4*)&xdbl[(size_t)gr * 96 + k4];
            Ash[rr][k4+0]=v.x; Ash[rr][k4+1]=v.y;
            Ash[rr][k4+2]=v.z; Ash[rr][k4+3]=v.w;
        }
        __syncthreads();
#pragma unroll
        for (int rr = 0; rr < 8; ++rr) {
            float acc = bv;
            const float* arow = Ash[half * 8 + rr];
            const float* bcol = Bsh[col];
#pragma unroll
            for (int k = 0; k < 64; ++k)
                acc = fmaf(arow[k], bcol[k], acc);
            const int grow = r0 + half * 128 + round * 8 + rr;
            const float sp = (acc > 20.f) ? acc : log1pf(expf(acc));
            dt[(size_t)grow * 2048 + n0 + col] = sp;
        }
        __syncthreads();
    }
}

// ---------------------------------------------------------------------------
// Depthwise causal conv (width 4) + bias + SiLU, 4 channels per thread.
// ---------------------------------------------------------------------------
__global__ __launch_bounds__(256) void conv_silu4(
    const float* __restrict__ xin, const float* __restrict__ w,
    const float* __restrict__ bias, float* __restrict__ xout,
    int L, int D)
{
    const long long e4 = (long long)blockIdx.x * 256 + threadIdx.x;
    const int Dq = D >> 2;
    const int dq = (int)(e4 % Dq);
    const long long bl = e4 / Dq;
    const int l = (int)(bl % L);
    const int d = dq << 2;
    const long long base = bl * D + d;

    const float4 zero = make_float4(0.f, 0.f, 0.f, 0.f);
    const float4 x0 = *(const float4*)&xin[base];
    const float4 x1 = (l >= 1) ? *(const float4*)&xin[base - D]     : zero;
    const float4 x2 = (l >= 2) ? *(const float4*)&xin[base - 2*D]   : zero;
    const float4 x3 = (l >= 3) ? *(const float4*)&xin[base - 3*D]   : zero;
    const float4 bv = *(const float4*)&bias[d];

    float4 out;
    {
        const float4 wv = *(const float4*)&w[(d + 0) * 4];
        float acc = bv.x;
        acc = fmaf(wv.w, x0.x, acc); acc = fmaf(wv.z, x1.x, acc);
        acc = fmaf(wv.y, x2.x, acc); acc = fmaf(wv.x, x3.x, acc);
        out.x = acc / (1.f + __expf(-acc));
    }
    {
        const float4 wv = *(const float4*)&w[(d + 1) * 4];
        float acc = bv.y;
        acc = fmaf(wv.w, x0.y, acc); acc = fmaf(wv.z, x1.y, acc);
        acc = fmaf(wv.y, x2.y, acc); acc = fmaf(wv.x, x3.y, acc);
        out.y = acc / (1.f + __expf(-acc));
    }
    {
        const float4 wv = *(const float4*)&w[(d + 2) * 4];
        float acc = bv.z;
        acc = fmaf(wv.w, x0.z, acc); acc = fmaf(wv.z, x1.z, acc);
        acc = fmaf(wv.y, x2.z, acc); acc = fmaf(wv.x, x3.z, acc);
        out.z = acc / (1.f + __expf(-acc));
    }
    {
        const float4 wv = *(const float4*)&w[(d + 3) * 4];
        float acc = bv.w;
        acc = fmaf(wv.w, x0.w, acc); acc = fmaf(wv.z, x1.w, acc);
        acc = fmaf(wv.y, x2.w, acc); acc = fmaf(wv.x, x3.w, acc);
        out.w = acc / (1.f + __expf(-acc));
    }
    *(float4*)&xout[base] = out;
}

// ---------------------------------------------------------------------------
// Scan pass 1 (per-channel): thread owns channel d, 16 states in registers.
// ---------------------------------------------------------------------------
__global__ __launch_bounds__(256) void scan_local2(
    const float* __restrict__ xconv, const float* __restrict__ dt,
    const float* __restrict__ xdbl,  const float* __restrict__ A_log,
    float* __restrict__ Sbuf, float* __restrict__ Pbuf)
{
    __shared__ float Bs[CH][16];

    const int d = blockIdx.x * 256 + threadIdx.x;
    const int c = blockIdx.y;
    const int b = blockIdx.z;
    const long long rowBase = (long long)b * 4096 + (long long)c * CH;

#pragma unroll
    for (int k = 0; k < 2; ++k) {
        const int e = k * 256 + threadIdx.x;
        const int i = e >> 2, j = (e & 3) << 2;
        *(float4*)&Bs[i][j] = *(const float4*)&xdbl[(rowBase + i) * 96 + 64 + j];
    }
    __syncthreads();

    float a[16], S[16];
#pragma unroll
    for (int n = 0; n < 16; ++n) {
        a[n] = -__expf(A_log[d * 16 + n]);
        S[n] = 0.f;
    }
    float sumdt = 0.f;

    for (int i = 0; i < CH; ++i) {
        const long long row = rowBase + i;
        const float dtv = dt[row * 2048 + d];
        const float xv  = xconv[row * 2048 + d];
        const float u   = dtv * xv;
        sumdt += dtv;
#pragma unroll
        for (int n = 0; n < 16; ++n) {
            const float dA = __expf(dtv * a[n]);
            S[n] = fmaf(S[n], dA, u * Bs[i][n]);
        }
    }

    const size_t base = ((((size_t)b * NC + c) * 2048) + d) * 16;
#pragma unroll
    for (int k = 0; k < 4; ++k) {
        *(float4*)&Sbuf[base + k * 4] =
            make_float4(S[k*4], S[k*4+1], S[k*4+2], S[k*4+3]);
        *(float4*)&Pbuf[base + k * 4] =
            make_float4(__expf(sumdt * a[k*4]),   __expf(sumdt * a[k*4+1]),
                        __expf(sumdt * a[k*4+2]), __expf(sumdt * a[k*4+3]));
    }
}

// ---------------------------------------------------------------------------
// Pass 2: sequential prefix over chunks; Sbuf becomes chunk-entering state.
// ---------------------------------------------------------------------------
__global__ __launch_bounds__(256) void scan_chunk_prefix(
    float* __restrict__ Sbuf, const float* __restrict__ Pbuf)
{
    const int tid = blockIdx.x * 256 + threadIdx.x;
    const int b  = tid >> 15;
    const int dn = tid & 32767;

    float H = 0.f;
    for (int c = 0; c < NC; ++c) {
        const size_t idx = ((size_t)b * NC + c) * 32768 + dn;
        const float S = Sbuf[idx];
        const float P = Pbuf[idx];
        Sbuf[idx] = H;
        H = fmaf(P, H, S);
    }
}

// ---------------------------------------------------------------------------
// Scan pass 3 (per-channel): seeded with H, gate, fp32 y in-place to xconv.
// ---------------------------------------------------------------------------
__global__ __launch_bounds__(256) void scan_final2(
    const float* __restrict__ xconv, const float* __restrict__ dt,
    const float* __restrict__ xdbl,  const float* __restrict__ A_log,
    const float* __restrict__ Dp,    const float* __restrict__ z,
    const float* __restrict__ Hbuf,  float* __restrict__ y)
{
    __shared__ float BCs[CH][32];    // [l][0..15]=B, [l][16..31]=C

    const int d = blockIdx.x * 256 + threadIdx.x;
    const int c = blockIdx.y;
    const int b = blockIdx.z;
    const long long rowBase = (long long)b * 4096 + (long long)c * CH;

#pragma unroll
    for (int k = 0; k < 4; ++k) {
        const int e = k * 256 + threadIdx.x;
        const int i = e >> 3, j = (e & 7) << 2;
        *(float4*)&BCs[i][j] = *(const float4*)&xdbl[(rowBase + i) * 96 + 64 + j];
    }
    __syncthreads();

    float a[16], h[16];
    const size_t hbase = ((((size_t)b * NC + c) * 2048) + d) * 16;
#pragma unroll
    for (int k = 0; k < 4; ++k) {
        const float4 hv = *(const float4*)&Hbuf[hbase + k * 4];
        h[k*4] = hv.x; h[k*4+1] = hv.y; h[k*4+2] = hv.z; h[k*4+3] = hv.w;
    }
#pragma unroll
    for (int n = 0; n < 16; ++n) a[n] = -__expf(A_log[d * 16 + n]);
    const float Dv = Dp[d];

    for (int i = 0; i < CH; ++i) {
        const long long row = rowBase + i;
        const float dtv = dt[row * 2048 + d];
        const float xv  = xconv[row * 2048 + d];
        const float u   = dtv * xv;
        float acc = 0.f;
#pragma unroll
        for (int n = 0; n < 16; ++n) {
            const float dA = __expf(dtv * a[n]);
            h[n] = fmaf(h[n], dA, u * BCs[i][n]);
            acc  = fmaf(h[n], BCs[i][16 + n], acc);
        }
        const float zv = z[row * 2048 + d];
        float yv = acc + xv * Dv;
        yv = yv * (zv / (1.f + __expf(-zv)));
        y[row * 2048 + d] = yv;
    }
}

// ---------------------------------------------------------------------------
extern "C" void kernel_launch(void* const* d_in, const int* in_sizes, int n_in,
                              void* d_out, int out_size, void* d_ws, size_t ws_size,
                              hipStream_t stream)
{
    const float* hidden     = (const float*)d_in[0];
    const float* in_proj_w  = (const float*)d_in[1];
    const float* conv_w     = (const float*)d_in[2];
    const float* conv_b     = (const float*)d_in[3];
    const float* x_proj_w   = (const float*)d_in[4];
    const float* dt_proj_w  = (const float*)d_in[5];
    const float* dt_proj_b  = (const float*)d_in[6];
    const float* A_log      = (const float*)d_in[7];
    const float* Dvec       = (const float*)d_in[8];
    const float* out_proj_w = (const float*)d_in[9];
    float* out = (float*)d_out;

    const int L = 4096, dinner = 2048, dmodel = 1024;
    const int M = 2 * L;  // 8192

    // ---- workspace layout: EXACTLY R2's proven 221.25 MB footprint ----
    float* z     = (float*)d_ws;                       // M*2048 fp32
    float* xraw  = z     + (size_t)M * dinner;         // M*2048 (x, xproj parts, dt)
    float* xconv = xraw  + (size_t)M * dinner;         // M*2048 (hid-pair, xconv, y)
    float* xdbl  = xconv + (size_t)M * dinner;         // M*96
    float* Sbuf  = xdbl  + (size_t)M * 96;             // 2*NC*2048*16
    float* Pbuf  = Sbuf  + (size_t)2 * NC * dinner * 16;

    // lifetime-disjoint aliases:
    bf16_t* w1_h  = (bf16_t*)Sbuf;                     // dead before scan
    bf16_t* w1_l  = w1_h + (size_t)2 * dinner * dmodel;
    bf16_t* hid_h = (bf16_t*)xconv;                    // dead at conv write
    bf16_t* hid_l = hid_h + (size_t)M * dmodel;
    float*  xp_part = xraw;                            // x_proj partials (xraw dead post-conv)
    bf16_t* w2_h  = (bf16_t*)z;                        // split after scan uses z
    bf16_t* w2_l  = w2_h + (size_t)dmodel * dinner;

    // ---- 0. pre-splits for in_proj ----
    split_hl<<<(2 * dinner * dmodel / 4 + 255) / 256, 256, 0, stream>>>(
        in_proj_w, w1_h, w1_l, 2 * dinner * dmodel / 4);
    split_hl<<<(M * dmodel / 4 + 255) / 256, 256, 0, stream>>>(
        hidden, hid_h, hid_l, M * dmodel / 4);

    // ---- 1a. in_proj x-half (3-term MFMA): rows 0..2047 of W -> x ----
    gemm_mfma3p<0><<<dim3(M / 128, 2048 / 128, 1), 256, 0, stream>>>(
        hid_h, hid_l, w1_h, w1_l, xraw, nullptr, 2048, dmodel, dmodel, 2048, 0);

    // ---- 1b. in_proj z-half (1-term bf16): rows 2048..4095 of W -> z ----
    gemm_bf16_1t<<<dim3(M / 128, 2048 / 128), 256, 0, stream>>>(
        hid_h, w1_h + (size_t)2048 * dmodel, z, dmodel, 2048);

    // ---- 2. depthwise conv + bias + SiLU (x4 vectorized) ----
    conv_silu4<<<(M * (long long)dinner / 4) / 256, 256, 0, stream>>>(
        xraw, conv_w, conv_b, xconv, L, dinner);

    // ---- 3. x_proj (fp32, split-K=8): partials -> add8 -> xdbl ----
    gemm_nt_sk<<<dim3(M / 64, 2, 8), 256, 0, stream>>>(
        xconv, x_proj_w, xp_part, 96, 2048 / 8, 2048, 2048, 96,
        (size_t)M * 96);
    add8<<<(M * 96 / 4 + 255) / 256, 256, 0, stream>>>(
        xp_part, xdbl, M * 96 / 4, (size_t)M * 96 / 4);

    // ---- 4. dt_proj (B-resident): softplus(xdbl[:,0:64] @ W^T + b) -> dt ----
    dt_proj_br<<<dim3(2048 / 128, M / 256), 256, 0, stream>>>(
        xdbl, dt_proj_w, dt_proj_b, xraw);

    // ---- 5. chunked selective scan (per-channel register-state form) ----
    scan_local2<<<dim3(dinner / 256, NC, 2), 256, 0, stream>>>(
        xconv, xraw, xdbl, A_log, Sbuf, Pbuf);
    scan_chunk_prefix<<<256, 256, 0, stream>>>(Sbuf, Pbuf);
    scan_final2<<<dim3(dinner / 256, NC, 2), 256, 0, stream>>>(
        xconv, xraw, xdbl, A_log, Dvec, z, Sbuf, xconv);

    // ---- 5b. split out_proj_w into bf16 hi/lo (into z region, now dead) ----
    split_hl<<<(dmodel * dinner / 4 + 255) / 256, 256, 0, stream>>>(
        out_proj_w, w2_h, w2_l, dmodel * dinner / 4);

    // ---- 6. out_proj: A=y fp32 reg-staged, 64x128 tile, direct store ----
    gemm_mfma3o<<<dim3(M / 64, 1024 / 128), 256, 0, stream>>>(
        xconv, w2_h, w2_l, out, dinner, 1024);
}

// Round 10
// 689.726 us; speedup vs baseline: 1.1869x; 1.0724x over previous
//
#include <hip/hip_runtime.h>
#include <cmath>

#define CH 128          // scan chunk length
#define NC 32           // 4096 / CH

typedef __bf16 bf16_t;
typedef __attribute__((ext_vector_type(8))) __bf16 bf16x8;
typedef __attribute__((ext_vector_type(4))) __bf16 bf16x4;
typedef __attribute__((ext_vector_type(4))) float f32x4;

// CK idiom: generic->AS1/AS3 via uintptr for global_load_lds (width 16).
#define GLOAD_LDS16(gp, lp)                                                     \
    __builtin_amdgcn_global_load_lds(                                           \
        (const __attribute__((address_space(1))) unsigned int*)(uintptr_t)(gp), \
        (__attribute__((address_space(3))) unsigned int*)(uintptr_t)(lp),       \
        16, 0, 0)

// ---------------------------------------------------------------------------
// fp32 -> (hi, lo) bf16 split.  4 floats per thread.
// ---------------------------------------------------------------------------
__global__ __launch_bounds__(256) void split_hl(
    const float* __restrict__ in, bf16_t* __restrict__ hi,
    bf16_t* __restrict__ lo, int n4)
{
    const int i = blockIdx.x * 256 + threadIdx.x;
    if (i >= n4) return;
    const float4 v = ((const float4*)in)[i];
    const bf16_t h0 = (bf16_t)v.x, h1 = (bf16_t)v.y,
                 h2 = (bf16_t)v.z, h3 = (bf16_t)v.w;
    bf16x4 hv = {h0, h1, h2, h3};
    bf16x4 lv = {(bf16_t)(v.x - (float)h0), (bf16_t)(v.y - (float)h1),
                 (bf16_t)(v.z - (float)h2), (bf16_t)(v.w - (float)h3)};
    ((bf16x4*)hi)[i] = hv;
    ((bf16x4*)lo)[i] = lv;
}

// ---------------------------------------------------------------------------
// x_proj split-K reduce + dt-slice hi/lo emit.
// p: 8 partials of [M][96]; o: xdbl fp32 [M][96];
// cols 0..63 additionally written as bf16 hi/lo pairs [M][64] (dt GEMM A).
// ---------------------------------------------------------------------------
__global__ __launch_bounds__(256) void add8_split(
    const float* __restrict__ p, float* __restrict__ o,
    bf16_t* __restrict__ dth, bf16_t* __restrict__ dtl,
    int n4, size_t stride4)
{
    const int i = blockIdx.x * 256 + threadIdx.x;
    if (i >= n4) return;
    float4 s = make_float4(0.f, 0.f, 0.f, 0.f);
#pragma unroll
    for (int k = 0; k < 8; ++k) {
        const float4 v = ((const float4*)p)[(size_t)k * stride4 + i];
        s.x += v.x; s.y += v.y; s.z += v.z; s.w += v.w;
    }
    ((float4*)o)[i] = s;

    const int col4 = i % 24;             // float4 col within the 96-wide row
    if (col4 < 16) {                     // dt slice (cols 0..63)
        const int row = i / 24;
        const bf16_t h0 = (bf16_t)s.x, h1 = (bf16_t)s.y,
                     h2 = (bf16_t)s.z, h3 = (bf16_t)s.w;
        bf16x4 hv = {h0, h1, h2, h3};
        bf16x4 lv = {(bf16_t)(s.x - (float)h0), (bf16_t)(s.y - (float)h1),
                     (bf16_t)(s.z - (float)h2), (bf16_t)(s.w - (float)h3)};
        ((bf16x4*)dth)[(size_t)row * 16 + col4] = hv;
        ((bf16x4*)dtl)[(size_t)row * 16 + col4] = lv;
    }
}

// ---------------------------------------------------------------------------
// Split-precision MFMA NT-GEMM, all-bf16 staging:
//   C = Ah.Bh^T + Al.Bh^T + Ah.Bl^T      (A fp32 ~= Ah + Al)
// 128x128 tile, BK=32, 4 waves, 4x4 frags mfma_f32_16x16x32_bf16,
// 48 MFMA / k-step, 8x global_load_lds width-16 staging, 32 KB LDS.
// EPI 0: C[m*ldc+n] = v.   EPI 2: v += bias[n]; softplus; store.
// ---------------------------------------------------------------------------
template<int EPI>
__global__ __launch_bounds__(256) void gemm_mfma3p(
    const bf16_t* __restrict__ Ah, const bf16_t* __restrict__ Al,
    const bf16_t* __restrict__ Bh, const bf16_t* __restrict__ Bl,
    float* __restrict__ C, const float* __restrict__ bias,
    int Ktot, int ldc)
{
    __shared__ __align__(16) bf16_t Ash[128 * 32];
    __shared__ __align__(16) bf16_t Asl[128 * 32];
    __shared__ __align__(16) bf16_t Bsh[128 * 32];
    __shared__ __align__(16) bf16_t Bsl[128 * 32];

    const int tid  = threadIdx.x;
    const int lane = tid & 63;
    const int w    = tid >> 6;
    const int wr   = (w >> 1) * 64;
    const int wc   = (w & 1) * 64;
    const int bm   = blockIdx.x * 128;
    const int bn   = blockIdx.y * 128;
    const int l16  = lane & 15;
    const int lhi  = lane >> 4;

    f32x4 acc[4][4];
#pragma unroll
    for (int i = 0; i < 4; ++i)
#pragma unroll
        for (int j = 0; j < 4; ++j)
#pragma unroll
            for (int r = 0; r < 4; ++r) acc[i][j][r] = 0.f;

    const int srow0 = tid >> 2;          // staging row, call 0
    const int sks   = (tid & 3) << 3;    // k element offset (8 bf16 = 16B)
    const int ldsb0 = tid * 16;          // linear LDS byte dest, call 0

    for (int k0 = 0; k0 < Ktot; k0 += 32) {
        __syncthreads();   // LDS reuse guard
#pragma unroll
        for (int call = 0; call < 2; ++call) {
            const int row = srow0 + call * 64;
            const int wb  = ldsb0 + call * 4096;
            const size_t aoff = (size_t)(bm + row) * Ktot + k0 + sks;
            const size_t boff = (size_t)(bn + row) * Ktot + k0 + sks;
            GLOAD_LDS16(Ah + aoff, (char*)Ash + wb);
            GLOAD_LDS16(Al + aoff, (char*)Asl + wb);
            GLOAD_LDS16(Bh + boff, (char*)Bsh + wb);
            GLOAD_LDS16(Bl + boff, (char*)Bsl + wb);
        }
        __syncthreads();   // compiler drains vmcnt before barrier

        bf16x8 ah[4], al[4], bh[4], bl[4];
#pragma unroll
        for (int f = 0; f < 4; ++f) {
            const int ar = (wr + f * 16 + l16) * 32 + lhi * 8;
            const int br = (wc + f * 16 + l16) * 32 + lhi * 8;
            ah[f] = *(const bf16x8*)&Ash[ar];
            al[f] = *(const bf16x8*)&Asl[ar];
            bh[f] = *(const bf16x8*)&Bsh[br];
            bl[f] = *(const bf16x8*)&Bsl[br];
        }
#pragma unroll
        for (int fm = 0; fm < 4; ++fm)
#pragma unroll
            for (int fn = 0; fn < 4; ++fn) {
                acc[fm][fn] = __builtin_amdgcn_mfma_f32_16x16x32_bf16(
                    ah[fm], bh[fn], acc[fm][fn], 0, 0, 0);
                acc[fm][fn] = __builtin_amdgcn_mfma_f32_16x16x32_bf16(
                    al[fm], bh[fn], acc[fm][fn], 0, 0, 0);
                acc[fm][fn] = __builtin_amdgcn_mfma_f32_16x16x32_bf16(
                    ah[fm], bl[fn], acc[fm][fn], 0, 0, 0);
            }
    }

    // epilogue: D col = lane&15, row = (lane>>4)*4 + reg  [m89-verified]
#pragma unroll
    for (int fm = 0; fm < 4; ++fm) {
        const int row0 = bm + wr + fm * 16 + lhi * 4;
#pragma unroll
        for (int fn = 0; fn < 4; ++fn) {
            const int col = bn + wc + fn * 16 + l16;
#pragma unroll
            for (int r = 0; r < 4; ++r) {
                float v = acc[fm][fn][r];
                const size_t m = row0 + r;
                if (EPI == 2) {
                    v += bias[col];
                    v = (v > 20.f) ? v : log1pf(expf(v));
                }
                C[m * ldc + col] = v;
            }
        }
    }
}

// ---------------------------------------------------------------------------
// Plain 1-term bf16 MFMA NT-GEMM (in_proj z-half): C = Ah.Bh^T.
// z is only consumed by the SiLU gate -> bf16 rounding error propagates to
// < ~3e-4 on the final output.  m97 structure.
// ---------------------------------------------------------------------------
__global__ __launch_bounds__(256) void gemm_bf16_1t(
    const bf16_t* __restrict__ Ah, const bf16_t* __restrict__ Bh,
    float* __restrict__ C, int Ktot, int ldc)
{
    __shared__ __align__(16) bf16_t Ash[128 * 32];
    __shared__ __align__(16) bf16_t Bsh[128 * 32];

    const int tid  = threadIdx.x;
    const int lane = tid & 63;
    const int w    = tid >> 6;
    const int wr   = (w >> 1) * 64;
    const int wc   = (w & 1) * 64;
    const int bm   = blockIdx.x * 128;
    const int bn   = blockIdx.y * 128;
    const int l16  = lane & 15;
    const int lhi  = lane >> 4;

    f32x4 acc[4][4];
#pragma unroll
    for (int i = 0; i < 4; ++i)
#pragma unroll
        for (int j = 0; j < 4; ++j)
#pragma unroll
            for (int r = 0; r < 4; ++r) acc[i][j][r] = 0.f;

    const int srow0 = tid >> 2;
    const int sks   = (tid & 3) << 3;
    const int ldsb0 = tid * 16;

    for (int k0 = 0; k0 < Ktot; k0 += 32) {
        __syncthreads();
#pragma unroll
        for (int call = 0; call < 2; ++call) {
            const int row = srow0 + call * 64;
            const int wb  = ldsb0 + call * 4096;
            GLOAD_LDS16(Ah + (size_t)(bm + row) * Ktot + k0 + sks, (char*)Ash + wb);
            GLOAD_LDS16(Bh + (size_t)(bn + row) * Ktot + k0 + sks, (char*)Bsh + wb);
        }
        __syncthreads();

        bf16x8 af[4], bf[4];
#pragma unroll
        for (int f = 0; f < 4; ++f) {
            af[f] = *(const bf16x8*)&Ash[(wr + f * 16 + l16) * 32 + lhi * 8];
            bf[f] = *(const bf16x8*)&Bsh[(wc + f * 16 + l16) * 32 + lhi * 8];
        }
#pragma unroll
        for (int fm = 0; fm < 4; ++fm)
#pragma unroll
            for (int fn = 0; fn < 4; ++fn)
                acc[fm][fn] = __builtin_amdgcn_mfma_f32_16x16x32_bf16(
                    af[fm], bf[fn], acc[fm][fn], 0, 0, 0);
    }

#pragma unroll
    for (int fm = 0; fm < 4; ++fm) {
        const int row0 = bm + wr + fm * 16 + lhi * 4;
#pragma unroll
        for (int fn = 0; fn < 4; ++fn) {
            const int col = bn + wc + fn * 16 + l16;
#pragma unroll
            for (int r = 0; r < 4; ++r)
                C[(size_t)(row0 + r) * ldc + col] = acc[fm][fn][r];
        }
    }
}

// ---------------------------------------------------------------------------
// out_proj GEMM: C = A.B^T, A [M][K] fp32 reg-staged (split to bf16 hi/lo
// in-kernel -> LDS), B pre-split bf16 pair via global_load_lds.
// 64x128 tile, BK=32, 4 waves (2x2), 2x4 frags, 24 MFMA/k-step.
// ---------------------------------------------------------------------------
__global__ __launch_bounds__(256) void gemm_mfma3o(
    const float* __restrict__ A,
    const bf16_t* __restrict__ Bh, const bf16_t* __restrict__ Bl,
    float* __restrict__ C, int K, int ldc)
{
    __shared__ __align__(16) bf16_t Ash[64 * 32];
    __shared__ __align__(16) bf16_t Asl[64 * 32];
    __shared__ __align__(16) bf16_t Bsh[128 * 32];
    __shared__ __align__(16) bf16_t Bsl[128 * 32];

    const int tid  = threadIdx.x;
    const int lane = tid & 63;
    const int w    = tid >> 6;
    const int wr   = (w >> 1) * 32;
    const int wc   = (w & 1) * 64;
    const int bm   = blockIdx.x * 64;
    const int bn   = blockIdx.y * 128;
    const int l16  = lane & 15;
    const int lhi  = lane >> 4;

    f32x4 acc[2][4];
#pragma unroll
    for (int i = 0; i < 2; ++i)
#pragma unroll
        for (int j = 0; j < 4; ++j)
#pragma unroll
            for (int r = 0; r < 4; ++r) acc[i][j][r] = 0.f;

    const int srowA = tid >> 2;
    const int sks   = (tid & 3) << 3;
    const int ldsb0 = tid * 16;

    for (int k0 = 0; k0 < K; k0 += 32) {
        __syncthreads();
#pragma unroll
        for (int call = 0; call < 2; ++call) {
            const int row = srowA + call * 64;
            const int wb  = ldsb0 + call * 4096;
            const size_t boff = (size_t)(bn + row) * K + k0 + sks;
            GLOAD_LDS16(Bh + boff, (char*)Bsh + wb);
            GLOAD_LDS16(Bl + boff, (char*)Bsl + wb);
        }
        {
            const float* ap = A + (size_t)(bm + srowA) * K + k0 + sks;
            const float4 v0 = *(const float4*)ap;
            const float4 v1 = *(const float4*)(ap + 4);
            const float fv[8] = {v0.x, v0.y, v0.z, v0.w, v1.x, v1.y, v1.z, v1.w};
            bf16x8 hv, lv;
#pragma unroll
            for (int e = 0; e < 8; ++e) {
                const bf16_t h = (bf16_t)fv[e];
                hv[e] = h;
                lv[e] = (bf16_t)(fv[e] - (float)h);
            }
            *(bf16x8*)((char*)Ash + ldsb0) = hv;
            *(bf16x8*)((char*)Asl + ldsb0) = lv;
        }
        __syncthreads();

        bf16x8 ah[2], al[2], bh[4], bl[4];
#pragma unroll
        for (int f = 0; f < 2; ++f) {
            const int ar = (wr + f * 16 + l16) * 32 + lhi * 8;
            ah[f] = *(const bf16x8*)&Ash[ar];
            al[f] = *(const bf16x8*)&Asl[ar];
        }
#pragma unroll
        for (int f = 0; f < 4; ++f) {
            const int br = (wc + f * 16 + l16) * 32 + lhi * 8;
            bh[f] = *(const bf16x8*)&Bsh[br];
            bl[f] = *(const bf16x8*)&Bsl[br];
        }
#pragma unroll
        for (int fm = 0; fm < 2; ++fm)
#pragma unroll
            for (int fn = 0; fn < 4; ++fn) {
                acc[fm][fn] = __builtin_amdgcn_mfma_f32_16x16x32_bf16(
                    ah[fm], bh[fn], acc[fm][fn], 0, 0, 0);
                acc[fm][fn] = __builtin_amdgcn_mfma_f32_16x16x32_bf16(
                    al[fm], bh[fn], acc[fm][fn], 0, 0, 0);
                acc[fm][fn] = __builtin_amdgcn_mfma_f32_16x16x32_bf16(
                    ah[fm], bl[fn], acc[fm][fn], 0, 0, 0);
            }
    }

#pragma unroll
    for (int fm = 0; fm < 2; ++fm) {
        const int row0 = bm + wr + fm * 16 + lhi * 4;
#pragma unroll
        for (int fn = 0; fn < 4; ++fn) {
            const int col = bn + wc + fn * 16 + l16;
#pragma unroll
            for (int r = 0; r < 4; ++r)
                C[(size_t)(row0 + r) * ldc + col] = acc[fm][fn][r];
        }
    }
}

// ---------------------------------------------------------------------------
// Tiled fp32 NT-GEMM with split-K (x_proj).  64x64 tile.
// ---------------------------------------------------------------------------
__global__ __launch_bounds__(256) void gemm_nt_sk(
    const float* __restrict__ A, const float* __restrict__ B,
    float* __restrict__ C,
    int N, int Ksplit, int lda, int ldb, int ldc, size_t partStride)
{
    __shared__ float As[16][68];
    __shared__ float Bs[16][68];

    const int tid = threadIdx.x;
    const int tx = tid & 15;
    const int ty = tid >> 4;
    const int bm = blockIdx.x * 64;
    const int bn = blockIdx.y * 64;

    const int r  = tid >> 2;
    const int kc = (tid & 3) << 2;

    float acc[4][4];
#pragma unroll
    for (int i = 0; i < 4; ++i)
#pragma unroll
        for (int j = 0; j < 4; ++j) acc[i][j] = 0.f;

    const int kBeg = blockIdx.z * Ksplit;
    const int kEnd = kBeg + Ksplit;

    for (int k0 = kBeg; k0 < kEnd; k0 += 16) {
        float4 av = *(const float4*)(A + (size_t)(bm + r) * lda + k0 + kc);
        const int cB = bn + r;
        float4 bv = make_float4(0.f, 0.f, 0.f, 0.f);
        if (cB < N) bv = *(const float4*)(B + (size_t)cB * ldb + k0 + kc);

        As[kc + 0][r] = av.x; As[kc + 1][r] = av.y;
        As[kc + 2][r] = av.z; As[kc + 3][r] = av.w;
        Bs[kc + 0][r] = bv.x; Bs[kc + 1][r] = bv.y;
        Bs[kc + 2][r] = bv.z; Bs[kc + 3][r] = bv.w;
        __syncthreads();

#pragma unroll
        for (int kk = 0; kk < 16; ++kk) {
            float4 a4 = *(const float4*)&As[kk][ty << 2];
            float4 b4 = *(const float4*)&Bs[kk][tx << 2];
            float a[4] = {a4.x, a4.y, a4.z, a4.w};
            float b[4] = {b4.x, b4.y, b4.z, b4.w};
#pragma unroll
            for (int i = 0; i < 4; ++i)
#pragma unroll
                for (int j = 0; j < 4; ++j)
                    acc[i][j] = fmaf(a[i], b[j], acc[i][j]);
        }
        __syncthreads();
    }

    float* Cp = C + (size_t)blockIdx.z * partStride;
#pragma unroll
    for (int i = 0; i < 4; ++i) {
        const int m = bm + (ty << 2) + i;
#pragma unroll
        for (int j = 0; j < 4; ++j) {
            const int n = bn + (tx << 2) + j;
            if (n < N) Cp[(size_t)m * ldc + n] = acc[i][j];
        }
    }
}

// ---------------------------------------------------------------------------
// Depthwise causal conv (width 4) + bias + SiLU, 4 channels per thread.
// ---------------------------------------------------------------------------
__global__ __launch_bounds__(256) void conv_silu4(
    const float* __restrict__ xin, const float* __restrict__ w,
    const float* __restrict__ bias, float* __restrict__ xout,
    int L, int D)
{
    const long long e4 = (long long)blockIdx.x * 256 + threadIdx.x;
    const int Dq = D >> 2;
    const int dq = (int)(e4 % Dq);
    const long long bl = e4 / Dq;
    const int l = (int)(bl % L);
    const int d = dq << 2;
    const long long base = bl * D + d;

    const float4 zero = make_float4(0.f, 0.f, 0.f, 0.f);
    const float4 x0 = *(const float4*)&xin[base];
    const float4 x1 = (l >= 1) ? *(const float4*)&xin[base - D]     : zero;
    const float4 x2 = (l >= 2) ? *(const float4*)&xin[base - 2*D]   : zero;
    const float4 x3 = (l >= 3) ? *(const float4*)&xin[base - 3*D]   : zero;
    const float4 bv = *(const float4*)&bias[d];

    float4 out;
    {
        const float4 wv = *(const float4*)&w[(d + 0) * 4];
        float acc = bv.x;
        acc = fmaf(wv.w, x0.x, acc); acc = fmaf(wv.z, x1.x, acc);
        acc = fmaf(wv.y, x2.x, acc); acc = fmaf(wv.x, x3.x, acc);
        out.x = acc / (1.f + __expf(-acc));
    }
    {
        const float4 wv = *(const float4*)&w[(d + 1) * 4];
        float acc = bv.y;
        acc = fmaf(wv.w, x0.y, acc); acc = fmaf(wv.z, x1.y, acc);
        acc = fmaf(wv.y, x2.y, acc); acc = fmaf(wv.x, x3.y, acc);
        out.y = acc / (1.f + __expf(-acc));
    }
    {
        const float4 wv = *(const float4*)&w[(d + 2) * 4];
        float acc = bv.z;
        acc = fmaf(wv.w, x0.z, acc); acc = fmaf(wv.z, x1.z, acc);
        acc = fmaf(wv.y, x2.z, acc); acc = fmaf(wv.x, x3.z, acc);
        out.z = acc / (1.f + __expf(-acc));
    }
    {
        const float4 wv = *(const float4*)&w[(d + 3) * 4];
        float acc = bv.w;
        acc = fmaf(wv.w, x0.w, acc); acc = fmaf(wv.z, x1.w, acc);
        acc = fmaf(wv.y, x2.w, acc); acc = fmaf(wv.x, x3.w, acc);
        out.w = acc / (1.f + __expf(-acc));
    }
    *(float4*)&xout[base] = out;
}

// ---------------------------------------------------------------------------
// Scan pass 1 (per-channel): thread owns channel d, 16 states in registers.
// ---------------------------------------------------------------------------
__global__ __launch_bounds__(256) void scan_local2(
    const float* __restrict__ xconv, const float* __restrict__ dt,
    const float* __restrict__ xdbl,  const float* __restrict__ A_log,
    float* __restrict__ Sbuf, float* __restrict__ Pbuf)
{
    __shared__ float Bs[CH][16];

    const int d = blockIdx.x * 256 + threadIdx.x;
    const int c = blockIdx.y;
    const int b = blockIdx.z;
    const long long rowBase = (long long)b * 4096 + (long long)c * CH;

#pragma unroll
    for (int k = 0; k < 2; ++k) {
        const int e = k * 256 + threadIdx.x;
        const int i = e >> 2, j = (e & 3) << 2;
        *(float4*)&Bs[i][j] = *(const float4*)&xdbl[(rowBase + i) * 96 + 64 + j];
    }
    __syncthreads();

    float a[16], S[16];
#pragma unroll
    for (int n = 0; n < 16; ++n) {
        a[n] = -__expf(A_log[d * 16 + n]);
        S[n] = 0.f;
    }
    float sumdt = 0.f;

    for (int i = 0; i < CH; ++i) {
        const long long row = rowBase + i;
        const float dtv = dt[row * 2048 + d];
        const float xv  = xconv[row * 2048 + d];
        const float u   = dtv * xv;
        sumdt += dtv;
#pragma unroll
        for (int n = 0; n < 16; ++n) {
            const float dA = __expf(dtv * a[n]);
            S[n] = fmaf(S[n], dA, u * Bs[i][n]);
        }
    }

    const size_t base = ((((size_t)b * NC + c) * 2048) + d) * 16;
#pragma unroll
    for (int k = 0; k < 4; ++k) {
        *(float4*)&Sbuf[base + k * 4] =
            make_float4(S[k*4], S[k*4+1], S[k*4+2], S[k*4+3]);
        *(float4*)&Pbuf[base + k * 4] =
            make_float4(__expf(sumdt * a[k*4]),   __expf(sumdt * a[k*4+1]),
                        __expf(sumdt * a[k*4+2]), __expf(sumdt * a[k*4+3]));
    }
}

// ---------------------------------------------------------------------------
// Pass 2: sequential prefix over chunks; Sbuf becomes chunk-entering state.
// ---------------------------------------------------------------------------
__global__ __launch_bounds__(256) void scan_chunk_prefix(
    float* __restrict__ Sbuf, const float* __restrict__ Pbuf)
{
    const int tid = blockIdx.x * 256 + threadIdx.x;
    const int b  = tid >> 15;
    const int dn = tid & 32767;

    float H = 0.f;
    for (int c = 0; c < NC; ++c) {
        const size_t idx = ((size_t)b * NC + c) * 32768 + dn;
        const float S = Sbuf[idx];
        const float P = Pbuf[idx];
        Sbuf[idx] = H;
        H = fmaf(P, H, S);
    }
}

// ---------------------------------------------------------------------------
// Scan pass 3 (per-channel): seeded with H, gate, fp32 y in-place to xconv.
// ---------------------------------------------------------------------------
__global__ __launch_bounds__(256) void scan_final2(
    const float* __restrict__ xconv, const float* __restrict__ dt,
    const float* __restrict__ xdbl,  const float* __restrict__ A_log,
    const float* __restrict__ Dp,    const float* __restrict__ z,
    const float* __restrict__ Hbuf,  float* __restrict__ y)
{
    __shared__ float BCs[CH][32];    // [l][0..15]=B, [l][16..31]=C

    const int d = blockIdx.x * 256 + threadIdx.x;
    const int c = blockIdx.y;
    const int b = blockIdx.z;
    const long long rowBase = (long long)b * 4096 + (long long)c * CH;

#pragma unroll
    for (int k = 0; k < 4; ++k) {
        const int e = k * 256 + threadIdx.x;
        const int i = e >> 3, j = (e & 7) << 2;
        *(float4*)&BCs[i][j] = *(const float4*)&xdbl[(rowBase + i) * 96 + 64 + j];
    }
    __syncthreads();

    float a[16], h[16];
    const size_t hbase = ((((size_t)b * NC + c) * 2048) + d) * 16;
#pragma unroll
    for (int k = 0; k < 4; ++k) {
        const float4 hv = *(const float4*)&Hbuf[hbase + k * 4];
        h[k*4] = hv.x; h[k*4+1] = hv.y; h[k*4+2] = hv.z; h[k*4+3] = hv.w;
    }
#pragma unroll
    for (int n = 0; n < 16; ++n) a[n] = -__expf(A_log[d * 16 + n]);
    const float Dv = Dp[d];

    for (int i = 0; i < CH; ++i) {
        const long long row = rowBase + i;
        const float dtv = dt[row * 2048 + d];
        const float xv  = xconv[row * 2048 + d];
        const float u   = dtv * xv;
        float acc = 0.f;
#pragma unroll
        for (int n = 0; n < 16; ++n) {
            const float dA = __expf(dtv * a[n]);
            h[n] = fmaf(h[n], dA, u * BCs[i][n]);
            acc  = fmaf(h[n], BCs[i][16 + n], acc);
        }
        const float zv = z[row * 2048 + d];
        float yv = acc + xv * Dv;
        yv = yv * (zv / (1.f + __expf(-zv)));
        y[row * 2048 + d] = yv;
    }
}

// ---------------------------------------------------------------------------
extern "C" void kernel_launch(void* const* d_in, const int* in_sizes, int n_in,
                              void* d_out, int out_size, void* d_ws, size_t ws_size,
                              hipStream_t stream)
{
    const float* hidden     = (const float*)d_in[0];
    const float* in_proj_w  = (const float*)d_in[1];
    const float* conv_w     = (const float*)d_in[2];
    const float* conv_b     = (const float*)d_in[3];
    const float* x_proj_w   = (const float*)d_in[4];
    const float* dt_proj_w  = (const float*)d_in[5];
    const float* dt_proj_b  = (const float*)d_in[6];
    const float* A_log      = (const float*)d_in[7];
    const float* Dvec       = (const float*)d_in[8];
    const float* out_proj_w = (const float*)d_in[9];
    float* out = (float*)d_out;

    const int L = 4096, dinner = 2048, dmodel = 1024;
    const int M = 2 * L;  // 8192

    // ---- workspace layout: EXACTLY R2's proven 221.25 MB footprint ----
    float* z     = (float*)d_ws;                       // M*2048 fp32
    float* xraw  = z     + (size_t)M * dinner;         // M*2048 (x, xproj parts, dt)
    float* xconv = xraw  + (size_t)M * dinner;         // M*2048 (hid-pair, xconv, y)
    float* xdbl  = xconv + (size_t)M * dinner;         // M*96
    float* Sbuf  = xdbl  + (size_t)M * 96;             // 2*NC*2048*16
    float* Pbuf  = Sbuf  + (size_t)2 * NC * dinner * 16;

    // lifetime-disjoint aliases:
    bf16_t* w1_h  = (bf16_t*)Sbuf;                     // in_proj weights (dead after 1b)
    bf16_t* w1_l  = w1_h + (size_t)2 * dinner * dmodel;
    bf16_t* hid_h = (bf16_t*)xconv;                    // dead at conv write
    bf16_t* hid_l = hid_h + (size_t)M * dmodel;
    float*  xp_part = xraw;                            // x_proj partials (xraw dead post-conv)
    // dt GEMM scratch lives in Sbuf region (w1 dead, Sbuf not yet written):
    bf16_t* dth  = (bf16_t*)Sbuf;                      // [M][64] bf16
    bf16_t* dtl  = dth + (size_t)M * 64;
    bf16_t* wdh  = dtl + (size_t)M * 64;               // [2048][64] bf16
    bf16_t* wdl  = wdh + (size_t)dinner * 64;
    bf16_t* w2_h  = (bf16_t*)z;                        // split after scan uses z
    bf16_t* w2_l  = w2_h + (size_t)dmodel * dinner;

    // ---- 0. pre-splits for in_proj ----
    split_hl<<<(2 * dinner * dmodel / 4 + 255) / 256, 256, 0, stream>>>(
        in_proj_w, w1_h, w1_l, 2 * dinner * dmodel / 4);
    split_hl<<<(M * dmodel / 4 + 255) / 256, 256, 0, stream>>>(
        hidden, hid_h, hid_l, M * dmodel / 4);

    // ---- 1a. in_proj x-half (3-term MFMA): rows 0..2047 of W -> x ----
    gemm_mfma3p<0><<<dim3(M / 128, 2048 / 128), 256, 0, stream>>>(
        hid_h, hid_l, w1_h, w1_l, xraw, nullptr, dmodel, 2048);

    // ---- 1b. in_proj z-half (1-term bf16): rows 2048..4095 of W -> z ----
    gemm_bf16_1t<<<dim3(M / 128, 2048 / 128), 256, 0, stream>>>(
        hid_h, w1_h + (size_t)2048 * dmodel, z, dmodel, 2048);

    // ---- 2. depthwise conv + bias + SiLU (x4 vectorized) ----
    conv_silu4<<<(M * (long long)dinner / 4) / 256, 256, 0, stream>>>(
        xraw, conv_w, conv_b, xconv, L, dinner);

    // ---- 3. x_proj (fp32, split-K=8): partials -> add8_split -> xdbl ----
    gemm_nt_sk<<<dim3(M / 64, 2, 8), 256, 0, stream>>>(
        xconv, x_proj_w, xp_part, 96, 2048 / 8, 2048, 2048, 96,
        (size_t)M * 96);
    add8_split<<<(M * 96 / 4 + 255) / 256, 256, 0, stream>>>(
        xp_part, xdbl, dth, dtl, M * 96 / 4, (size_t)M * 96 / 4);

    // ---- 4. dt_proj (3-term MFMA, K=64): softplus(dt@W^T + b) -> xraw ----
    split_hl<<<(dinner * 64 / 4 + 255) / 256, 256, 0, stream>>>(
        dt_proj_w, wdh, wdl, dinner * 64 / 4);
    gemm_mfma3p<2><<<dim3(M / 128, 2048 / 128), 256, 0, stream>>>(
        dth, dtl, wdh, wdl, xraw, dt_proj_b, 64, 2048);

    // ---- 5. chunked selective scan (per-channel register-state form) ----
    scan_local2<<<dim3(dinner / 256, NC, 2), 256, 0, stream>>>(
        xconv, xraw, xdbl, A_log, Sbuf, Pbuf);
    scan_chunk_prefix<<<256, 256, 0, stream>>>(Sbuf, Pbuf);
    scan_final2<<<dim3(dinner / 256, NC, 2), 256, 0, stream>>>(
        xconv, xraw, xdbl, A_log, Dvec, z, Sbuf, xconv);

    // ---- 5b. split out_proj_w into bf16 hi/lo (into z region, now dead) ----
    split_hl<<<(dmodel * dinner / 4 + 255) / 256, 256, 0, stream>>>(
        out_proj_w, w2_h, w2_l, dmodel * dinner / 4);

    // ---- 6. out_proj: A=y fp32 reg-staged, 64x128 tile, direct store ----
    gemm_mfma3o<<<dim3(M / 64, 1024 / 128), 256, 0, stream>>>(
        xconv, w2_h, w2_l, out, dinner, 1024);
}